// Round 4
// baseline (1605.363 us; speedup 1.0000x reference)
//
#include <hip/hip_runtime.h>
#include <hip/hip_cooperative_groups.h>

namespace cg = cooperative_groups;

#define DIM 256
#define GRP 16
#define LEV0 9   // levels LEV0..LEV0+NLEV-1 use the grouped path (N=16383 tree)
#define NLEV 4
#define MPAD 260 // mean_s row stride; +4 pad -> 2-way bank aliasing (free)
#define GBLK 1024

#define FMA4(a, sc, v) \
    a.x = fmaf((sc), (v).x, a.x); a.y = fmaf((sc), (v).y, a.y); \
    a.z = fmaf((sc), (v).z, a.z); a.w = fmaf((sc), (v).w, a.w);

// ======================= fused cooperative kernel =======================
__global__ __launch_bounds__(256, 4) void fused_kernel(
    const int* __restrict__ x_sym, const float* __restrict__ W,
    const float* __restrict__ b, float* __restrict__ enc,
    int* __restrict__ order, const float* __restrict__ W_out,
    const float* __restrict__ b_out, float* __restrict__ out)
{
    cg::grid_group grid = cg::this_grid();
    __shared__ float  mean_s[GRP][MPAD];   // 16.6 KB
    __shared__ float4 part_s[4][4][64];    // 16 KB
    __shared__ int cnt_s[16], cur_s[16];

    const int t = threadIdx.x;
    const int w = t >> 6;
    const int lane = t & 63;
    const int bid = blockIdx.x;
    const int NB = gridDim.x;

    // ---- sort: block li buckets level LEV0+li nodes by symbol ----
    if (bid < NLEV) {
        const int li = bid;
        const int d = LEV0 + li;
        const int lo = (1 << d) - 1;
        const int n  = 1 << d;
        int off = 0;
        for (int k = 0; k < li; ++k) off += (1 << (LEV0 + k)) + 240;
        const int cap = n + 240;
        for (int i = t; i < cap; i += 256) order[off + i] = -1;
        if (t < 16) cnt_s[t] = 0;
        __syncthreads();
        for (int i = t; i < n; i += 256) atomicAdd(&cnt_s[x_sym[lo + i]], 1);
        __syncthreads();
        if (t == 0) {
            int run = off;
            for (int s2 = 0; s2 < 16; ++s2) {
                cur_s[s2] = run;
                run += ((cnt_s[s2] + GRP - 1) / GRP) * GRP;
            }
        }
        __syncthreads();
        for (int i = t; i < n; i += 256) {
            const int pos = atomicAdd(&cur_s[x_sym[lo + i]], 1);
            order[pos] = lo + i;
        }
    }
    grid.sync();

    // ---- grouped levels 12..9: 16 same-symbol nodes x 64 cols per item ----
    for (int d = LEV0 + NLEV - 1; d >= LEV0; --d) {
        const int li = d - LEV0;
        int off = 0;
        for (int k = 0; k < li; ++k) off += (1 << (LEV0 + k)) + 240;
        const int items = ((1 << d) / GRP + 15) * 4;
        const int leafc = (d == LEV0 + NLEV - 1) ? 1 : 0;  // d==12: children are leaves
        for (int it = bid; it < items; it += NB) {
            const int grp  = it >> 2;
            const int tile = it & 3;
            const int base = off + grp * GRP;
            const int n0 = order[base];
            if (n0 < 0) continue;              // block-uniform padding group
            const int s = x_sym[n0];
            // stage means: wave w stages nodes w*4+j over all 256 cols
            {
                const int c = lane << 2;
                #pragma unroll
                for (int j = 0; j < 4; ++j) {
                    const int node = order[base + w * 4 + j];
                    float4 m = make_float4(0.f, 0.f, 0.f, 0.f);
                    if (node >= 0) {
                        const int c0 = 2 * node + 1;
                        if (leafc) {  // leaf child: enc = tanh(b[sym])
                            const int sa = x_sym[c0], sb = x_sym[c0 + 1];
                            const float4 ba = *(const float4*)(b + sa * DIM + c);
                            const float4 bb = *(const float4*)(b + sb * DIM + c);
                            m.x = 0.5f * (tanhf(ba.x) + tanhf(bb.x));
                            m.y = 0.5f * (tanhf(ba.y) + tanhf(bb.y));
                            m.z = 0.5f * (tanhf(ba.z) + tanhf(bb.z));
                            m.w = 0.5f * (tanhf(ba.w) + tanhf(bb.w));
                        } else {
                            const float4 ea = *(const float4*)(enc + (size_t)c0 * DIM + c);
                            const float4 eb = *(const float4*)(enc + (size_t)(c0 + 1) * DIM + c);
                            m.x = 0.5f * (ea.x + eb.x);
                            m.y = 0.5f * (ea.y + eb.y);
                            m.z = 0.5f * (ea.z + eb.z);
                            m.w = 0.5f * (ea.w + eb.w);
                        }
                    }
                    *(float4*)(&mean_s[w * 4 + j][c]) = m;
                }
            }
            __syncthreads();
            // compute: wave w = K chunk [64w,64w+64); lane -> 4 nodes x 4 cols
            const int ns4 = (lane >> 4) << 2;
            const int g4  = (lane & 15) << 2;
            const float* __restrict__ Ws =
                W + ((size_t)s << 16) + (size_t)(w * 64) * DIM + tile * 64 + g4;
            float4 acc0 = make_float4(0, 0, 0, 0), acc1 = acc0, acc2 = acc0, acc3 = acc0;
            const int dbase = w * 64;
            #pragma unroll 4
            for (int dd = 0; dd < 64; dd += 4) {
                const float4 w0 = *(const float4*)(Ws + (size_t)(dd + 0) * DIM);
                const float4 w1 = *(const float4*)(Ws + (size_t)(dd + 1) * DIM);
                const float4 w2 = *(const float4*)(Ws + (size_t)(dd + 2) * DIM);
                const float4 w3 = *(const float4*)(Ws + (size_t)(dd + 3) * DIM);
                const int dk = dbase + dd;
                const float4 m0 = *(const float4*)(&mean_s[ns4 + 0][dk]);
                const float4 m1 = *(const float4*)(&mean_s[ns4 + 1][dk]);
                const float4 m2 = *(const float4*)(&mean_s[ns4 + 2][dk]);
                const float4 m3 = *(const float4*)(&mean_s[ns4 + 3][dk]);
                FMA4(acc0, m0.x, w0); FMA4(acc0, m0.y, w1); FMA4(acc0, m0.z, w2); FMA4(acc0, m0.w, w3);
                FMA4(acc1, m1.x, w0); FMA4(acc1, m1.y, w1); FMA4(acc1, m1.z, w2); FMA4(acc1, m1.w, w3);
                FMA4(acc2, m2.x, w0); FMA4(acc2, m2.y, w1); FMA4(acc2, m2.z, w2); FMA4(acc2, m2.w, w3);
                FMA4(acc3, m3.x, w0); FMA4(acc3, m3.y, w1); FMA4(acc3, m3.z, w2); FMA4(acc3, m3.w, w3);
            }
            part_s[w][0][lane] = acc0;
            part_s[w][1][lane] = acc1;
            part_s[w][2][lane] = acc2;
            part_s[w][3][lane] = acc3;
            __syncthreads();
            // finalize: thread (w,lane) -> node ns4+w, cols tile*64+g4
            const int node_g = order[base + ns4 + w];
            if (node_g >= 0) {
                float4 r        = part_s[0][w][lane];
                const float4 p1 = part_s[1][w][lane];
                const float4 p2 = part_s[2][w][lane];
                const float4 p3 = part_s[3][w][lane];
                const float4 bs = *(const float4*)(b + s * DIM + tile * 64 + g4);
                r.x = tanhf(r.x + p1.x + p2.x + p3.x + bs.x);
                r.y = tanhf(r.y + p1.y + p2.y + p3.y + bs.y);
                r.z = tanhf(r.z + p1.z + p2.z + p3.z + bs.z);
                r.w = tanhf(r.w + p1.w + p2.w + p3.w + bs.w);
                *(float4*)(enc + (size_t)node_g * DIM + tile * 64 + g4) = r;
            }
        }
        grid.sync();
    }

    // ---- small levels 8..0: item = (node, 64-col tile), 4-way K split ----
    {
        float* smean = (float*)&mean_s[0][0];       // 256 floats
        float* spart = (float*)&part_s[0][0][0];    // 256 floats
        for (int d = LEV0 - 1; d >= 0; --d) {
            const int lo = (1 << d) - 1;
            const int items = (1 << d) * 4;
            for (int it = bid; it < items; it += NB) {
                const int node = lo + (it >> 2);
                const int tile = it & 3;
                const int c = tile * 64 + lane;
                const int s = x_sym[node];
                const int c0 = 2 * node + 1;
                smean[t] = 0.5f * (enc[(size_t)c0 * DIM + t] + enc[(size_t)(c0 + 1) * DIM + t]);
                __syncthreads();
                float acc = 0.0f;
                const float* __restrict__ Ws = W + ((size_t)s << 16);
                const int d0 = w * 64;
                #pragma unroll 8
                for (int k = d0; k < d0 + 64; ++k)
                    acc = fmaf(smean[k], Ws[(size_t)k * DIM + c], acc);
                spart[t] = acc;
                __syncthreads();
                if (t < 64) {
                    float r = spart[t] + spart[t + 64] + spart[t + 128] + spart[t + 192];
                    r += b[s * DIM + c];
                    enc[(size_t)node * DIM + c] = tanhf(r);
                }
            }
            grid.sync();
        }
    }

    // ---- head: block 0, out = enc[root] @ W_out + b_out ----
    if (bid == 0) {
        const float e = enc[t];
        float p[10];
        #pragma unroll
        for (int o = 0; o < 10; ++o) p[o] = e * W_out[t * 10 + o];
        #pragma unroll
        for (int o = 0; o < 10; ++o)
            #pragma unroll
            for (int k = 32; k >= 1; k >>= 1) p[o] += __shfl_xor(p[o], k, 64);
        float* hp = (float*)&part_s[0][0][0];   // 40 floats
        if (lane == 0) {
            #pragma unroll
            for (int o = 0; o < 10; ++o) hp[w * 10 + o] = p[o];
        }
        __syncthreads();
        if (t < 10) out[t] = b_out[t] + hp[t] + hp[10 + t] + hp[20 + t] + hp[30 + t];
    }
}

// ======================= fallback multi-launch path =======================
__global__ __launch_bounds__(1024) void sort_kernel(const int* __restrict__ x_sym,
                                                    int* __restrict__ order) {
    __shared__ int cnt_s[NLEV * 16];
    __shared__ int cur_s[NLEV * 16];
    const int t = threadIdx.x;
    const int CAP = ((1 << (LEV0 + NLEV)) - (1 << LEV0)) + NLEV * 240;
    for (int i = t; i < CAP; i += 1024) order[i] = -1;
    if (t < NLEV * 16) cnt_s[t] = 0;
    __syncthreads();
    const int lo = (1 << LEV0) - 1, hi = (1 << (LEV0 + NLEV)) - 1;
    for (int i = lo + t; i < hi; i += 1024) {
        const int li = (31 - __clz(i + 1)) - LEV0;
        atomicAdd(&cnt_s[li * 16 + x_sym[i]], 1);
    }
    __syncthreads();
    if (t < NLEV) {
        int run = 0;
        for (int k = 0; k < t; ++k) run += (1 << (LEV0 + k)) + 240;
        for (int s2 = 0; s2 < 16; ++s2) {
            cur_s[t * 16 + s2] = run;
            run += ((cnt_s[t * 16 + s2] + GRP - 1) / GRP) * GRP;
        }
    }
    __syncthreads();
    for (int i = lo + t; i < hi; i += 1024) {
        const int li = (31 - __clz(i + 1)) - LEV0;
        const int pos = atomicAdd(&cur_s[li * 16 + x_sym[i]], 1);
        order[pos] = i;
    }
}

__global__ __launch_bounds__(256) void level_grouped(const int* __restrict__ x_sym,
                                                     const float* __restrict__ W,
                                                     const float* __restrict__ b,
                                                     float* __restrict__ enc,
                                                     const int* __restrict__ order,
                                                     int level_off, int leaf_children) {
    const int grp  = blockIdx.x >> 2;
    const int tile = blockIdx.x & 3;
    const int base = level_off + grp * GRP;
    const int n0 = order[base];
    if (n0 < 0) return;
    const int s = x_sym[n0];
    const int t = threadIdx.x;
    const int w = t >> 6;
    const int lane = t & 63;

    __shared__ float  mean_s[GRP][MPAD];
    __shared__ float4 part_s[4][4][64];

    {
        const int c = lane << 2;
        #pragma unroll
        for (int j = 0; j < 4; ++j) {
            const int node = order[base + w * 4 + j];
            float4 m = make_float4(0.f, 0.f, 0.f, 0.f);
            if (node >= 0) {
                const int c0 = 2 * node + 1;
                if (leaf_children) {
                    const int sa = x_sym[c0], sb = x_sym[c0 + 1];
                    const float4 ba = *(const float4*)(b + sa * DIM + c);
                    const float4 bb = *(const float4*)(b + sb * DIM + c);
                    m.x = 0.5f * (tanhf(ba.x) + tanhf(bb.x));
                    m.y = 0.5f * (tanhf(ba.y) + tanhf(bb.y));
                    m.z = 0.5f * (tanhf(ba.z) + tanhf(bb.z));
                    m.w = 0.5f * (tanhf(ba.w) + tanhf(bb.w));
                } else {
                    const float4 ea = *(const float4*)(enc + (size_t)c0 * DIM + c);
                    const float4 eb = *(const float4*)(enc + (size_t)(c0 + 1) * DIM + c);
                    m.x = 0.5f * (ea.x + eb.x);
                    m.y = 0.5f * (ea.y + eb.y);
                    m.z = 0.5f * (ea.z + eb.z);
                    m.w = 0.5f * (ea.w + eb.w);
                }
            }
            *(float4*)(&mean_s[w * 4 + j][c]) = m;
        }
    }
    __syncthreads();

    const int ns4 = (lane >> 4) << 2;
    const int g4  = (lane & 15) << 2;
    const float* __restrict__ Ws =
        W + ((size_t)s << 16) + (size_t)(w * 64) * DIM + tile * 64 + g4;
    float4 acc0 = make_float4(0, 0, 0, 0), acc1 = acc0, acc2 = acc0, acc3 = acc0;
    const int dbase = w * 64;
    #pragma unroll 4
    for (int dd = 0; dd < 64; dd += 4) {
        const float4 w0 = *(const float4*)(Ws + (size_t)(dd + 0) * DIM);
        const float4 w1 = *(const float4*)(Ws + (size_t)(dd + 1) * DIM);
        const float4 w2 = *(const float4*)(Ws + (size_t)(dd + 2) * DIM);
        const float4 w3 = *(const float4*)(Ws + (size_t)(dd + 3) * DIM);
        const int d = dbase + dd;
        const float4 m0 = *(const float4*)(&mean_s[ns4 + 0][d]);
        const float4 m1 = *(const float4*)(&mean_s[ns4 + 1][d]);
        const float4 m2 = *(const float4*)(&mean_s[ns4 + 2][d]);
        const float4 m3 = *(const float4*)(&mean_s[ns4 + 3][d]);
        FMA4(acc0, m0.x, w0); FMA4(acc0, m0.y, w1); FMA4(acc0, m0.z, w2); FMA4(acc0, m0.w, w3);
        FMA4(acc1, m1.x, w0); FMA4(acc1, m1.y, w1); FMA4(acc1, m1.z, w2); FMA4(acc1, m1.w, w3);
        FMA4(acc2, m2.x, w0); FMA4(acc2, m2.y, w1); FMA4(acc2, m2.z, w2); FMA4(acc2, m2.w, w3);
        FMA4(acc3, m3.x, w0); FMA4(acc3, m3.y, w1); FMA4(acc3, m3.z, w2); FMA4(acc3, m3.w, w3);
    }
    part_s[w][0][lane] = acc0;
    part_s[w][1][lane] = acc1;
    part_s[w][2][lane] = acc2;
    part_s[w][3][lane] = acc3;
    __syncthreads();

    const int node_g = order[base + ns4 + w];
    if (node_g >= 0) {
        float4 r        = part_s[0][w][lane];
        const float4 p1 = part_s[1][w][lane];
        const float4 p2 = part_s[2][w][lane];
        const float4 p3 = part_s[3][w][lane];
        const float4 bs = *(const float4*)(b + s * DIM + tile * 64 + g4);
        r.x = tanhf(r.x + p1.x + p2.x + p3.x + bs.x);
        r.y = tanhf(r.y + p1.y + p2.y + p3.y + bs.y);
        r.z = tanhf(r.z + p1.z + p2.z + p3.z + bs.z);
        r.w = tanhf(r.w + p1.w + p2.w + p3.w + bs.w);
        *(float4*)(enc + (size_t)node_g * DIM + tile * 64 + g4) = r;
    }
}

__global__ __launch_bounds__(256) void level_small(const int* __restrict__ x_sym,
                                                   const float* __restrict__ W,
                                                   const float* __restrict__ b,
                                                   float* __restrict__ enc,
                                                   int lo, int N) {
    const int node = lo + (blockIdx.x >> 2);
    const int tile = blockIdx.x & 3;
    const int t = threadIdx.x;
    const int lane = t & 63;
    const int c = tile * 64 + lane;

    __shared__ float mean_s[DIM];
    __shared__ float part[256];

    const int s = x_sym[node];
    const int c0 = 2 * node + 1;

    float m = 0.0f;
    if (c0 < N)
        m = 0.5f * (enc[(size_t)c0 * DIM + t] + enc[(size_t)(c0 + 1) * DIM + t]);
    mean_s[t] = m;
    __syncthreads();

    float acc = 0.0f;
    if (c0 < N) {
        const float* __restrict__ Ws = W + ((size_t)s << 16);
        const int d0 = (t >> 6) * 64;
        #pragma unroll 8
        for (int d = d0; d < d0 + 64; ++d)
            acc = fmaf(mean_s[d], Ws[d * DIM + c], acc);
    }
    part[t] = acc;
    __syncthreads();

    if (t < 64) {
        float r = part[t] + part[t + 64] + part[t + 128] + part[t + 192];
        r += b[s * DIM + c];
        enc[(size_t)node * DIM + c] = tanhf(r);
    }
}

__global__ __launch_bounds__(256) void level_big(const int* __restrict__ x_sym,
                                                 const float* __restrict__ W,
                                                 const float* __restrict__ b,
                                                 float* __restrict__ enc,
                                                 int lo, int N) {
    const int node = lo + blockIdx.x;
    const int e = threadIdx.x;
    __shared__ float mean_s[DIM];
    const int s = x_sym[node];
    const int c0 = 2 * node + 1;

    float acc = b[s * DIM + e];
    if (c0 < N) {
        mean_s[e] = 0.5f * (enc[(size_t)c0 * DIM + e] + enc[(size_t)(c0 + 1) * DIM + e]);
        __syncthreads();
        const float* __restrict__ Ws = W + ((size_t)s << 16);
        #pragma unroll 8
        for (int d = 0; d < DIM; ++d)
            acc = fmaf(mean_s[d], Ws[d * DIM + e], acc);
    }
    enc[(size_t)node * DIM + e] = tanhf(acc);
}

__global__ __launch_bounds__(256) void out_kernel10(const float* __restrict__ enc,
                                                    const float* __restrict__ W_out,
                                                    const float* __restrict__ b_out,
                                                    float* __restrict__ out) {
    const int t = threadIdx.x;
    const float e = enc[t];
    float p[10];
    #pragma unroll
    for (int o = 0; o < 10; ++o) p[o] = e * W_out[t * 10 + o];
    #pragma unroll
    for (int o = 0; o < 10; ++o)
        #pragma unroll
        for (int k = 32; k >= 1; k >>= 1) p[o] += __shfl_xor(p[o], k, 64);
    __shared__ float part[4][10];
    if ((t & 63) == 0) {
        #pragma unroll
        for (int o = 0; o < 10; ++o) part[t >> 6][o] = p[o];
    }
    __syncthreads();
    if (t < 10) out[t] = b_out[t] + part[0][t] + part[1][t] + part[2][t] + part[3][t];
}

__global__ void out_kernel(const float* __restrict__ enc,
                           const float* __restrict__ W_out,
                           const float* __restrict__ b_out,
                           float* __restrict__ out, int outn) {
    const int o = threadIdx.x;
    if (o < outn) {
        float acc = b_out[o];
        for (int d = 0; d < DIM; ++d)
            acc = fmaf(enc[d], W_out[d * outn + o], acc);
        out[o] = acc;
    }
}

extern "C" void kernel_launch(void* const* d_in, const int* in_sizes, int n_in,
                              void* d_out, int out_size, void* d_ws, size_t ws_size,
                              hipStream_t stream) {
    const int*   x_sym = (const int*)d_in[0];
    const float* W     = (const float*)d_in[2];
    const float* b     = (const float*)d_in[3];
    const float* W_out = (const float*)d_in[4];
    const float* b_out = (const float*)d_in[5];
    float* out = (float*)d_out;
    float* enc = (float*)d_ws;                      // N x 256 fp32
    const int N = in_sizes[0];

    int depth = 0;
    while (((1 << depth) - 1) < N) ++depth;

    if (N == (1 << 14) - 1 && out_size == 10) {
        int* order = (int*)(enc + (size_t)N * DIM);  // 8640 ints
        void* args[] = { (void*)&x_sym, (void*)&W, (void*)&b, (void*)&enc,
                         (void*)&order, (void*)&W_out, (void*)&b_out, (void*)&out };
        hipError_t err = hipLaunchCooperativeKernel((const void*)fused_kernel,
                                                    dim3(GBLK), dim3(256),
                                                    args, 0, stream);
        if (err == hipSuccess) return;
        (void)hipGetLastError();  // clear; fall back to multi-launch path

        sort_kernel<<<1, 1024, 0, stream>>>(x_sym, order);
        for (int d = LEV0 + NLEV - 1; d >= LEV0; --d) {
            const int li = d - LEV0;
            int off = 0;
            for (int k = 0; k < li; ++k) off += (1 << (LEV0 + k)) + 240;
            const int blocks = ((1 << d) / GRP + 15) * 4;
            level_grouped<<<blocks, 256, 0, stream>>>(x_sym, W, b, enc, order, off,
                                                      (d == depth - 2) ? 1 : 0);
        }
        for (int d = LEV0 - 1; d >= 0; --d) {
            const int lo = (1 << d) - 1;
            const int n = (1 << d);
            level_small<<<n * 4, 256, 0, stream>>>(x_sym, W, b, enc, lo, N);
        }
        out_kernel10<<<1, 256, 0, stream>>>(enc, W_out, b_out, out);
    } else {
        for (int d = depth - 1; d >= 0; --d) {
            int lo = (1 << d) - 1;
            int n = (1 << d);
            if (lo + n > N) n = N - lo;
            if (n >= 256)
                level_big<<<n, 256, 0, stream>>>(x_sym, W, b, enc, lo, N);
            else
                level_small<<<n * 4, 256, 0, stream>>>(x_sym, W, b, enc, lo, N);
        }
        out_kernel<<<1, 64, 0, stream>>>(enc, W_out, b_out, out, out_size);
    }
}

// Round 5
// 1303.403 us; speedup vs baseline: 1.2317x; 1.2317x over previous
//
#include <hip/hip_runtime.h>

#define DIM 256
#define GRP 16
#define LEV0 9   // levels LEV0..LEV0+NLEV-1 use the grouped path (N=16383 tree)
#define NLEV 4
#define MPAD 260 // mean_s row stride; +4 pad -> 2-way bank aliasing (free)
#define NBLK 1024

#define FMA4(a, sc, v) \
    a.x = fmaf((sc), (v).x, a.x); a.y = fmaf((sc), (v).y, a.y); \
    a.z = fmaf((sc), (v).z, a.z); a.w = fmaf((sc), (v).w, a.w;)

#undef FMA4
#define FMA4(a, sc, v) \
    a.x = fmaf((sc), (v).x, a.x); a.y = fmaf((sc), (v).y, a.y); \
    a.z = fmaf((sc), (v).z, a.z); a.w = fmaf((sc), (v).w, a.w);

// ---- custom grid barrier ----
// bar layout (ints): leaf l, slot k -> bar[l*32+k]; root k -> bar[512+k];
// gen k -> bar[640+k*32]. Slots are single-use per launch; kernel_launch
// memsets the region so graph replays are deterministic.
__device__ __forceinline__ void gbar(int* __restrict__ bar, int k, int P, int bid) {
    __syncthreads();
    if (threadIdx.x == 0) {
        __threadfence();  // make this block's enc writes visible (agent scope)
        int* genp = bar + 640 + k * 32;
        bool rel = false;
        if (P >= 16) {                    // tree: 16 leaves, P/16 arrivals each
            const int lc = P >> 4;
            const int v = __hip_atomic_fetch_add(bar + ((bid & 15) * 32 + k), 1,
                                                 __ATOMIC_ACQ_REL, __HIP_MEMORY_SCOPE_AGENT);
            if (v == lc - 1) {
                const int r = __hip_atomic_fetch_add(bar + (512 + k), 1,
                                                     __ATOMIC_ACQ_REL, __HIP_MEMORY_SCOPE_AGENT);
                if (r == 15) {
                    __hip_atomic_store(genp, 1, __ATOMIC_RELEASE, __HIP_MEMORY_SCOPE_AGENT);
                    rel = true;
                }
            }
        } else {                          // small barrier: root only
            const int v = __hip_atomic_fetch_add(bar + (512 + k), 1,
                                                 __ATOMIC_ACQ_REL, __HIP_MEMORY_SCOPE_AGENT);
            if (v == P - 1) {
                __hip_atomic_store(genp, 1, __ATOMIC_RELEASE, __HIP_MEMORY_SCOPE_AGENT);
                rel = true;
            }
        }
        if (!rel) {
            int guard = 0;
            while (__hip_atomic_load(genp, __ATOMIC_ACQUIRE, __HIP_MEMORY_SCOPE_AGENT) == 0) {
                __builtin_amdgcn_s_sleep(8);
                if (++guard > (1 << 22)) break;   // safety: never hang the harness
            }
        }
        __threadfence();
    }
    __syncthreads();
}

// ======================= fused persistent kernel =======================
__global__ __launch_bounds__(256, 4) void fused_kernel(
    const int* __restrict__ x_sym, const float* __restrict__ W,
    const float* __restrict__ b, float* __restrict__ enc,
    int* __restrict__ order, int* __restrict__ bar,
    const float* __restrict__ W_out, const float* __restrict__ b_out,
    float* __restrict__ out)
{
    __shared__ float  mean_s[GRP][MPAD];   // 16.6 KB
    __shared__ float4 part_s[4][4][64];    // 16 KB
    __shared__ int cnt_s[16], cur_s[16];

    const int t = threadIdx.x;
    const int w = t >> 6;
    const int lane = t & 63;
    const int bid = blockIdx.x;
    int kbar = 0;

    // ---- sort: block li buckets level LEV0+li nodes by symbol ----
    if (bid < NLEV) {
        const int li = bid;
        const int d = LEV0 + li;
        const int lo = (1 << d) - 1;
        const int n  = 1 << d;
        int off = 0;
        for (int k = 0; k < li; ++k) off += (1 << (LEV0 + k)) + 240;
        const int cap = n + 240;
        for (int i = t; i < cap; i += 256) order[off + i] = -1;
        if (t < 16) cnt_s[t] = 0;
        __syncthreads();
        for (int i = t; i < n; i += 256) atomicAdd(&cnt_s[x_sym[lo + i]], 1);
        __syncthreads();
        if (t == 0) {
            int run = off;
            for (int s2 = 0; s2 < 16; ++s2) {
                cur_s[s2] = run;
                run += ((cnt_s[s2] + GRP - 1) / GRP) * GRP;
            }
        }
        __syncthreads();
        for (int i = t; i < n; i += 256) {
            const int pos = atomicAdd(&cur_s[x_sym[lo + i]], 1);
            order[pos] = lo + i;
        }
    }
    gbar(bar, kbar++, NBLK, bid);

    // ---- grouped levels 12..9: 16 same-symbol nodes x 64 cols per item ----
    for (int d = LEV0 + NLEV - 1; d >= LEV0; --d) {
        const int li = d - LEV0;
        int off = 0;
        for (int k = 0; k < li; ++k) off += (1 << (LEV0 + k)) + 240;
        const int items = ((1 << d) / GRP + 15) * 4;
        const int leafc = (d == LEV0 + NLEV - 1) ? 1 : 0;  // d==12: children are leaves
        for (int it = bid; it < items; it += NBLK) {
            const int grp  = it >> 2;
            const int tile = it & 3;
            const int base = off + grp * GRP;
            const int n0 = order[base];
            if (n0 < 0) continue;              // block-uniform padding group
            const int s = x_sym[n0];
            // stage means: wave w stages nodes w*4+j over all 256 cols
            {
                const int c = lane << 2;
                #pragma unroll
                for (int j = 0; j < 4; ++j) {
                    const int node = order[base + w * 4 + j];
                    float4 m = make_float4(0.f, 0.f, 0.f, 0.f);
                    if (node >= 0) {
                        const int c0 = 2 * node + 1;
                        if (leafc) {  // leaf child: enc = tanh(b[sym])
                            const int sa = x_sym[c0], sb = x_sym[c0 + 1];
                            const float4 ba = *(const float4*)(b + sa * DIM + c);
                            const float4 bb = *(const float4*)(b + sb * DIM + c);
                            m.x = 0.5f * (tanhf(ba.x) + tanhf(bb.x));
                            m.y = 0.5f * (tanhf(ba.y) + tanhf(bb.y));
                            m.z = 0.5f * (tanhf(ba.z) + tanhf(bb.z));
                            m.w = 0.5f * (tanhf(ba.w) + tanhf(bb.w));
                        } else {
                            const float4 ea = *(const float4*)(enc + (size_t)c0 * DIM + c);
                            const float4 eb = *(const float4*)(enc + (size_t)(c0 + 1) * DIM + c);
                            m.x = 0.5f * (ea.x + eb.x);
                            m.y = 0.5f * (ea.y + eb.y);
                            m.z = 0.5f * (ea.z + eb.z);
                            m.w = 0.5f * (ea.w + eb.w);
                        }
                    }
                    *(float4*)(&mean_s[w * 4 + j][c]) = m;
                }
            }
            __syncthreads();
            // compute: wave w = K chunk [64w,64w+64); lane -> 4 nodes x 4 cols
            const int ns4 = (lane >> 4) << 2;
            const int g4  = (lane & 15) << 2;
            const float* __restrict__ Ws =
                W + ((size_t)s << 16) + (size_t)(w * 64) * DIM + tile * 64 + g4;
            float4 acc0 = make_float4(0, 0, 0, 0), acc1 = acc0, acc2 = acc0, acc3 = acc0;
            const int dbase = w * 64;
            #pragma unroll 4
            for (int dd = 0; dd < 64; dd += 4) {
                const float4 w0 = *(const float4*)(Ws + (size_t)(dd + 0) * DIM);
                const float4 w1 = *(const float4*)(Ws + (size_t)(dd + 1) * DIM);
                const float4 w2 = *(const float4*)(Ws + (size_t)(dd + 2) * DIM);
                const float4 w3 = *(const float4*)(Ws + (size_t)(dd + 3) * DIM);
                const int dk = dbase + dd;
                const float4 m0 = *(const float4*)(&mean_s[ns4 + 0][dk]);
                const float4 m1 = *(const float4*)(&mean_s[ns4 + 1][dk]);
                const float4 m2 = *(const float4*)(&mean_s[ns4 + 2][dk]);
                const float4 m3 = *(const float4*)(&mean_s[ns4 + 3][dk]);
                FMA4(acc0, m0.x, w0); FMA4(acc0, m0.y, w1); FMA4(acc0, m0.z, w2); FMA4(acc0, m0.w, w3);
                FMA4(acc1, m1.x, w0); FMA4(acc1, m1.y, w1); FMA4(acc1, m1.z, w2); FMA4(acc1, m1.w, w3);
                FMA4(acc2, m2.x, w0); FMA4(acc2, m2.y, w1); FMA4(acc2, m2.z, w2); FMA4(acc2, m2.w, w3);
                FMA4(acc3, m3.x, w0); FMA4(acc3, m3.y, w1); FMA4(acc3, m3.z, w2); FMA4(acc3, m3.w, w3);
            }
            part_s[w][0][lane] = acc0;
            part_s[w][1][lane] = acc1;
            part_s[w][2][lane] = acc2;
            part_s[w][3][lane] = acc3;
            __syncthreads();
            // finalize: thread (w,lane) -> node ns4+w, cols tile*64+g4
            const int node_g = order[base + ns4 + w];
            if (node_g >= 0) {
                float4 r        = part_s[0][w][lane];
                const float4 p1 = part_s[1][w][lane];
                const float4 p2 = part_s[2][w][lane];
                const float4 p3 = part_s[3][w][lane];
                const float4 bs = *(const float4*)(b + s * DIM + tile * 64 + g4);
                r.x = tanhf(r.x + p1.x + p2.x + p3.x + bs.x);
                r.y = tanhf(r.y + p1.y + p2.y + p3.y + bs.y);
                r.z = tanhf(r.z + p1.z + p2.z + p3.z + bs.z);
                r.w = tanhf(r.w + p1.w + p2.w + p3.w + bs.w);
                *(float4*)(enc + (size_t)node_g * DIM + tile * 64 + g4) = r;
            }
            __syncthreads();
        }
        gbar(bar, kbar++, NBLK, bid);
    }

    // ---- small levels 8..0: item = (node, 64-col tile), shrinking grid ----
    {
        float* smean = (float*)&mean_s[0][0];       // 256 floats
        float* spart = (float*)&part_s[0][0][0];    // 256 floats
        for (int d = LEV0 - 1; d >= 0; --d) {
            const int lo = (1 << d) - 1;
            const int items = 4 << d;               // alive blocks == items
            if (bid < items) {
                const int node = lo + (bid >> 2);
                const int tile = bid & 3;
                const int c = tile * 64 + lane;
                const int s = x_sym[node];
                const int c0 = 2 * node + 1;
                smean[t] = 0.5f * (enc[(size_t)c0 * DIM + t] + enc[(size_t)(c0 + 1) * DIM + t]);
                __syncthreads();
                float acc = 0.0f;
                const float* __restrict__ Ws = W + ((size_t)s << 16);
                const int d0 = w * 64;
                #pragma unroll 8
                for (int k = d0; k < d0 + 64; ++k)
                    acc = fmaf(smean[k], Ws[(size_t)k * DIM + c], acc);
                spart[t] = acc;
                __syncthreads();
                if (t < 64) {
                    float r = spart[t] + spart[t + 64] + spart[t + 128] + spart[t + 192];
                    r += b[s * DIM + c];
                    enc[(size_t)node * DIM + c] = tanhf(r);
                }
            }
            gbar(bar, kbar++, items, bid);
            if (d > 0 && bid >= (items >> 1)) return;   // retire: no work left
        }
    }

    // ---- head: block 0, out = enc[root] @ W_out + b_out ----
    if (bid == 0) {
        const float e = enc[t];
        float p[10];
        #pragma unroll
        for (int o = 0; o < 10; ++o) p[o] = e * W_out[t * 10 + o];
        #pragma unroll
        for (int o = 0; o < 10; ++o)
            #pragma unroll
            for (int k = 32; k >= 1; k >>= 1) p[o] += __shfl_xor(p[o], k, 64);
        float* hp = (float*)&part_s[0][0][0];   // 40 floats
        if (lane == 0) {
            #pragma unroll
            for (int o = 0; o < 10; ++o) hp[w * 10 + o] = p[o];
        }
        __syncthreads();
        if (t < 10) out[t] = b_out[t] + hp[t] + hp[10 + t] + hp[20 + t] + hp[30 + t];
    }
}

// ======================= fallback multi-launch path =======================
__global__ __launch_bounds__(256) void level_small(const int* __restrict__ x_sym,
                                                   const float* __restrict__ W,
                                                   const float* __restrict__ b,
                                                   float* __restrict__ enc,
                                                   int lo, int N) {
    const int node = lo + (blockIdx.x >> 2);
    const int tile = blockIdx.x & 3;
    const int t = threadIdx.x;
    const int lane = t & 63;
    const int c = tile * 64 + lane;

    __shared__ float mean_s[DIM];
    __shared__ float part[256];

    const int s = x_sym[node];
    const int c0 = 2 * node + 1;

    float m = 0.0f;
    if (c0 < N)
        m = 0.5f * (enc[(size_t)c0 * DIM + t] + enc[(size_t)(c0 + 1) * DIM + t]);
    mean_s[t] = m;
    __syncthreads();

    float acc = 0.0f;
    if (c0 < N) {
        const float* __restrict__ Ws = W + ((size_t)s << 16);
        const int d0 = (t >> 6) * 64;
        #pragma unroll 8
        for (int d = d0; d < d0 + 64; ++d)
            acc = fmaf(mean_s[d], Ws[d * DIM + c], acc);
    }
    part[t] = acc;
    __syncthreads();

    if (t < 64) {
        float r = part[t] + part[t + 64] + part[t + 128] + part[t + 192];
        r += b[s * DIM + c];
        enc[(size_t)node * DIM + c] = tanhf(r);
    }
}

__global__ __launch_bounds__(256) void level_big(const int* __restrict__ x_sym,
                                                 const float* __restrict__ W,
                                                 const float* __restrict__ b,
                                                 float* __restrict__ enc,
                                                 int lo, int N) {
    const int node = lo + blockIdx.x;
    const int e = threadIdx.x;
    __shared__ float mean_s[DIM];
    const int s = x_sym[node];
    const int c0 = 2 * node + 1;

    float acc = b[s * DIM + e];
    if (c0 < N) {
        mean_s[e] = 0.5f * (enc[(size_t)c0 * DIM + e] + enc[(size_t)(c0 + 1) * DIM + e]);
        __syncthreads();
        const float* __restrict__ Ws = W + ((size_t)s << 16);
        #pragma unroll 8
        for (int d = 0; d < DIM; ++d)
            acc = fmaf(mean_s[d], Ws[d * DIM + e], acc);
    }
    enc[(size_t)node * DIM + e] = tanhf(acc);
}

__global__ void out_kernel(const float* __restrict__ enc,
                           const float* __restrict__ W_out,
                           const float* __restrict__ b_out,
                           float* __restrict__ out, int outn) {
    const int o = threadIdx.x;
    if (o < outn) {
        float acc = b_out[o];
        for (int d = 0; d < DIM; ++d)
            acc = fmaf(enc[d], W_out[d * outn + o], acc);
        out[o] = acc;
    }
}

extern "C" void kernel_launch(void* const* d_in, const int* in_sizes, int n_in,
                              void* d_out, int out_size, void* d_ws, size_t ws_size,
                              hipStream_t stream) {
    const int*   x_sym = (const int*)d_in[0];
    const float* W     = (const float*)d_in[2];
    const float* b     = (const float*)d_in[3];
    const float* W_out = (const float*)d_in[4];
    const float* b_out = (const float*)d_in[5];
    float* out = (float*)d_out;
    float* enc = (float*)d_ws;                      // N x 256 fp32
    const int N = in_sizes[0];

    int depth = 0;
    while (((1 << depth) - 1) < N) ++depth;

    if (N == (1 << 14) - 1 && out_size == 10) {
        int* order = (int*)(enc + (size_t)N * DIM);  // 8640 ints
        int* bar   = order + 8640;                   // 1280 ints of barrier state
        hipMemsetAsync(bar, 0, 5120, stream);        // deterministic per replay
        fused_kernel<<<NBLK, 256, 0, stream>>>(x_sym, W, b, enc, order, bar,
                                               W_out, b_out, out);
    } else {
        for (int d = depth - 1; d >= 0; --d) {
            int lo = (1 << d) - 1;
            int n = (1 << d);
            if (lo + n > N) n = N - lo;
            if (n >= 256)
                level_big<<<n, 256, 0, stream>>>(x_sym, W, b, enc, lo, N);
            else
                level_small<<<n * 4, 256, 0, stream>>>(x_sym, W, b, enc, lo, N);
        }
        out_kernel<<<1, 64, 0, stream>>>(enc, W_out, b_out, out, out_size);
    }
}

// Round 6
// 143.652 us; speedup vs baseline: 11.1754x; 9.0733x over previous
//
#include <hip/hip_runtime.h>

#define DIM 256
#define GRP 16
#define LEV0 9   // levels LEV0..LEV0+NLEV-1 use the grouped path (N=16383 tree)
#define NLEV 4
#define MPAD 260 // mean_s row stride; +4 pad -> 2-way bank aliasing (free)
#define NBLK 1024

#define FMA4(a, sc, v) \
    a.x = fmaf((sc), (v).x, a.x); a.y = fmaf((sc), (v).y, a.y); \
    a.z = fmaf((sc), (v).z, a.z); a.w = fmaf((sc), (v).w, a.w);

// ---- agent-coherent (cross-XCD) accessors; LLC is the coherence point ----
__device__ __forceinline__ float2 ld2(const float* p) {
    union { unsigned long long u; float2 f; } cv;
    cv.u = __hip_atomic_load((const unsigned long long*)p, __ATOMIC_RELAXED,
                             __HIP_MEMORY_SCOPE_AGENT);
    return cv.f;
}
__device__ __forceinline__ void st2(float* p, float x, float y) {
    union { unsigned long long u; float2 f; } cv;
    cv.f = make_float2(x, y);
    __hip_atomic_store((unsigned long long*)p, cv.u, __ATOMIC_RELAXED,
                       __HIP_MEMORY_SCOPE_AGENT);
}
__device__ __forceinline__ float ld1(const float* p) {
    union { unsigned int u; float f; } cv;
    cv.u = __hip_atomic_load((const unsigned int*)p, __ATOMIC_RELAXED,
                             __HIP_MEMORY_SCOPE_AGENT);
    return cv.f;
}
__device__ __forceinline__ void st1f(float* p, float x) {
    union { unsigned int u; float f; } cv; cv.f = x;
    __hip_atomic_store((unsigned int*)p, cv.u, __ATOMIC_RELAXED,
                       __HIP_MEMORY_SCOPE_AGENT);
}
__device__ __forceinline__ int ldi(const int* p) {
    return __hip_atomic_load(p, __ATOMIC_RELAXED, __HIP_MEMORY_SCOPE_AGENT);
}
__device__ __forceinline__ void sti(int* p, int v) {
    __hip_atomic_store(p, v, __ATOMIC_RELAXED, __HIP_MEMORY_SCOPE_AGENT);
}
__device__ __forceinline__ int addi(int* p) {
    return __hip_atomic_fetch_add(p, 1, __ATOMIC_RELAXED, __HIP_MEMORY_SCOPE_AGENT);
}
__device__ __forceinline__ void spin(const int* f) {
    int guard = 0;
    while (__hip_atomic_load(f, __ATOMIC_RELAXED, __HIP_MEMORY_SCOPE_AGENT) == 0) {
        __builtin_amdgcn_s_sleep(2);
        if (++guard > (1 << 20)) break;   // never hard-hang the harness
    }
}

// ======================= fused flag-driven kernel =======================
__global__ __launch_bounds__(256, 4) void fused_kernel(
    const int* __restrict__ x_sym, const float* __restrict__ W,
    const float* __restrict__ b, float* __restrict__ enc,
    int* __restrict__ order, int* __restrict__ flg, int* __restrict__ cnt,
    int* __restrict__ done, const float* __restrict__ W_out,
    const float* __restrict__ b_out, float* __restrict__ out)
{
    __shared__ float  mean_s[GRP][MPAD];   // 16.6 KB
    __shared__ float4 part_s[4][4][64];    // 16 KB
    __shared__ int cnt_s[16], cur_s[16];

    const int t = threadIdx.x;
    const int w = t >> 6;
    const int lane = t & 63;
    const int bid = blockIdx.x;

    // ---- sort: block li buckets level LEV0+li by symbol, publishes 64 done lines ----
    if (bid < NLEV) {
        const int li = bid;
        const int d = LEV0 + li;
        const int lo = (1 << d) - 1;
        const int n  = 1 << d;
        int off = 0;
        for (int k = 0; k < li; ++k) off += (1 << (LEV0 + k)) + 240;
        for (int i = t; i < n + 240; i += 256) sti(&order[off + i], -1);
        if (t < 16) cnt_s[t] = 0;
        __syncthreads();
        for (int i = t; i < n; i += 256) atomicAdd(&cnt_s[x_sym[lo + i]], 1);
        __syncthreads();
        if (t == 0) {
            int run = off;
            for (int s2 = 0; s2 < 16; ++s2) {
                cur_s[s2] = run;
                run += ((cnt_s[s2] + GRP - 1) / GRP) * GRP;
            }
        }
        __syncthreads();
        for (int i = t; i < n; i += 256) {
            const int pos = atomicAdd(&cur_s[x_sym[lo + i]], 1);
            sti(&order[pos], lo + i);
        }
        __syncthreads();   // vmcnt(0) drained -> order visible at LLC
        if (t < 64) sti(&done[li * 64 + t], 1);
    }

    // ---- grouped levels 12..9: 16 same-symbol nodes x 64 cols per item ----
    for (int li = NLEV - 1; li >= 0; --li) {
        const int d = LEV0 + li;
        int off = 0;
        for (int k = 0; k < li; ++k) off += (1 << (LEV0 + k)) + 240;
        const int items = ((1 << d) / GRP + 15) * 4;
        if (bid >= items) continue;
        const int leafc = (li == NLEV - 1) ? 1 : 0;   // d==12: children are leaves
        if (t == 0) spin(&done[li * 64 + (bid & 63)]);
        __syncthreads();
        for (int it = bid; it < items; it += NBLK) {
            const int grp  = it >> 2;
            const int tile = it & 3;
            const int base = off + grp * GRP;
            const int n0 = ldi(&order[base]);          // uniform across block
            // wait for the 32 children of this group (levels 11..9 only)
            if (!leafc && n0 >= 0 && t < 32) {
                const int gn = ldi(&order[base + (t >> 1)]);
                if (gn >= 0) spin(&flg[2 * gn + 1 + (t & 1)]);
            }
            __syncthreads();
            if (n0 >= 0) {   // uniform branch
                const int s = x_sym[n0];
                // stage means: wave w stages nodes w*4+j over all 256 cols
                const int c = lane << 2;
                #pragma unroll
                for (int j = 0; j < 4; ++j) {
                    const int node = ldi(&order[base + w * 4 + j]);
                    float4 m = make_float4(0.f, 0.f, 0.f, 0.f);
                    if (node >= 0) {
                        const int c0 = 2 * node + 1;
                        if (leafc) {   // leaf child: enc = tanh(b[sym])
                            const int sa = x_sym[c0], sb = x_sym[c0 + 1];
                            const float4 ba = *(const float4*)(b + sa * DIM + c);
                            const float4 bb = *(const float4*)(b + sb * DIM + c);
                            m.x = 0.5f * (tanhf(ba.x) + tanhf(bb.x));
                            m.y = 0.5f * (tanhf(ba.y) + tanhf(bb.y));
                            m.z = 0.5f * (tanhf(ba.z) + tanhf(bb.z));
                            m.w = 0.5f * (tanhf(ba.w) + tanhf(bb.w));
                        } else {
                            const float2 a0 = ld2(enc + (size_t)c0 * DIM + c);
                            const float2 a1 = ld2(enc + (size_t)c0 * DIM + c + 2);
                            const float2 b0 = ld2(enc + (size_t)(c0 + 1) * DIM + c);
                            const float2 b1 = ld2(enc + (size_t)(c0 + 1) * DIM + c + 2);
                            m.x = 0.5f * (a0.x + b0.x);
                            m.y = 0.5f * (a0.y + b0.y);
                            m.z = 0.5f * (a1.x + b1.x);
                            m.w = 0.5f * (a1.y + b1.y);
                        }
                    }
                    *(float4*)(&mean_s[w * 4 + j][c]) = m;
                }
            }
            __syncthreads();
            if (n0 >= 0) {
                // compute: wave w = K chunk [64w,64w+64); lane -> 4 nodes x 4 cols
                const int ns4 = (lane >> 4) << 2;
                const int g4  = (lane & 15) << 2;
                const float* __restrict__ Ws =
                    W + ((size_t)x_sym[n0] << 16) + (size_t)(w * 64) * DIM + tile * 64 + g4;
                float4 acc0 = make_float4(0, 0, 0, 0), acc1 = acc0, acc2 = acc0, acc3 = acc0;
                const int dbase = w * 64;
                #pragma unroll 4
                for (int dd = 0; dd < 64; dd += 4) {
                    const float4 w0 = *(const float4*)(Ws + (size_t)(dd + 0) * DIM);
                    const float4 w1 = *(const float4*)(Ws + (size_t)(dd + 1) * DIM);
                    const float4 w2 = *(const float4*)(Ws + (size_t)(dd + 2) * DIM);
                    const float4 w3 = *(const float4*)(Ws + (size_t)(dd + 3) * DIM);
                    const int dk = dbase + dd;
                    const float4 m0 = *(const float4*)(&mean_s[ns4 + 0][dk]);
                    const float4 m1 = *(const float4*)(&mean_s[ns4 + 1][dk]);
                    const float4 m2 = *(const float4*)(&mean_s[ns4 + 2][dk]);
                    const float4 m3 = *(const float4*)(&mean_s[ns4 + 3][dk]);
                    FMA4(acc0, m0.x, w0); FMA4(acc0, m0.y, w1); FMA4(acc0, m0.z, w2); FMA4(acc0, m0.w, w3);
                    FMA4(acc1, m1.x, w0); FMA4(acc1, m1.y, w1); FMA4(acc1, m1.z, w2); FMA4(acc1, m1.w, w3);
                    FMA4(acc2, m2.x, w0); FMA4(acc2, m2.y, w1); FMA4(acc2, m2.z, w2); FMA4(acc2, m2.w, w3);
                    FMA4(acc3, m3.x, w0); FMA4(acc3, m3.y, w1); FMA4(acc3, m3.z, w2); FMA4(acc3, m3.w, w3);
                }
                part_s[w][0][lane] = acc0;
                part_s[w][1][lane] = acc1;
                part_s[w][2][lane] = acc2;
                part_s[w][3][lane] = acc3;
            }
            __syncthreads();
            if (n0 >= 0) {
                // finalize: thread (w,lane) -> node ns4+w, cols tile*64+g4
                const int ns4 = (lane >> 4) << 2;
                const int g4  = (lane & 15) << 2;
                const int node_g = ldi(&order[base + ns4 + w]);
                if (node_g >= 0) {
                    float4 r        = part_s[0][w][lane];
                    const float4 p1 = part_s[1][w][lane];
                    const float4 p2 = part_s[2][w][lane];
                    const float4 p3 = part_s[3][w][lane];
                    const int s = x_sym[n0];
                    const float4 bs = *(const float4*)(b + s * DIM + tile * 64 + g4);
                    r.x = tanhf(r.x + p1.x + p2.x + p3.x + bs.x);
                    r.y = tanhf(r.y + p1.y + p2.y + p3.y + bs.y);
                    r.z = tanhf(r.z + p1.z + p2.z + p3.z + bs.z);
                    r.w = tanhf(r.w + p1.w + p2.w + p3.w + bs.w);
                    float* ep = enc + (size_t)node_g * DIM + tile * 64 + g4;
                    st2(ep, r.x, r.y);
                    st2(ep + 2, r.z, r.w);
                }
            }
            __syncthreads();   // vmcnt(0): all 256 threads' enc stores at LLC
            if (n0 >= 0 && t < 16) {
                const int ng = ldi(&order[base + t]);
                if (ng >= 0 && addi(&cnt[ng]) == 3) sti(&flg[ng], 1);
            }
        }
    }

    // ---- small levels 8..0: item = (node, 64-col tile); blocks retire ----
    {
        float* smean = (float*)&mean_s[0][0];       // 256 floats
        float* spart = (float*)&part_s[0][0][0];    // 256 floats
        for (int d = LEV0 - 1; d >= 0; --d) {
            const int items = 4 << d;
            if (bid >= items) return;               // retired forever
            const int lo = (1 << d) - 1;
            const int node = lo + (bid >> 2);
            const int tile = bid & 3;
            const int c0 = 2 * node + 1;
            if (t < 2) spin(&flg[c0 + t]);
            __syncthreads();
            const int s = x_sym[node];
            smean[t] = 0.5f * (ld1(enc + (size_t)c0 * DIM + t) +
                               ld1(enc + (size_t)(c0 + 1) * DIM + t));
            __syncthreads();
            float acc = 0.0f;
            const float* __restrict__ Ws = W + ((size_t)s << 16);
            const int d0 = w * 64;
            const int cc = tile * 64 + lane;
            #pragma unroll 8
            for (int k = d0; k < d0 + 64; ++k)
                acc = fmaf(smean[k], Ws[(size_t)k * DIM + cc], acc);
            spart[t] = acc;
            __syncthreads();
            if (t < 64) {
                float r = spart[t] + spart[t + 64] + spart[t + 128] + spart[t + 192];
                r += b[s * DIM + cc];
                st1f(enc + (size_t)node * DIM + cc, tanhf(r));
            }
            __syncthreads();   // vmcnt(0): enc stores at LLC
            if (t == 0 && addi(&cnt[node]) == 3) sti(&flg[node], 1);
            __syncthreads();   // protect smean/spart reuse next level
        }
        // head: block 0
        if (bid == 0) {
            if (t == 0) spin(&flg[0]);
            __syncthreads();
            const float e = ld1(enc + t);
            float p[10];
            #pragma unroll
            for (int o = 0; o < 10; ++o) p[o] = e * W_out[t * 10 + o];
            #pragma unroll
            for (int o = 0; o < 10; ++o)
                #pragma unroll
                for (int k = 32; k >= 1; k >>= 1) p[o] += __shfl_xor(p[o], k, 64);
            float* hp = (float*)&part_s[0][0][0];
            if (lane == 0) {
                #pragma unroll
                for (int o = 0; o < 10; ++o) hp[w * 10 + o] = p[o];
            }
            __syncthreads();
            if (t < 10) out[t] = b_out[t] + hp[t] + hp[10 + t] + hp[20 + t] + hp[30 + t];
        }
    }
}

// ======================= fallback multi-launch path (proven, round 3) =======================
__global__ __launch_bounds__(1024) void sort_kernel(const int* __restrict__ x_sym,
                                                    int* __restrict__ order) {
    __shared__ int cnt_s[NLEV * 16];
    __shared__ int cur_s[NLEV * 16];
    const int t = threadIdx.x;
    const int CAP = ((1 << (LEV0 + NLEV)) - (1 << LEV0)) + NLEV * 240;
    for (int i = t; i < CAP; i += 1024) order[i] = -1;
    if (t < NLEV * 16) cnt_s[t] = 0;
    __syncthreads();
    const int lo = (1 << LEV0) - 1, hi = (1 << (LEV0 + NLEV)) - 1;
    for (int i = lo + t; i < hi; i += 1024) {
        const int li = (31 - __clz(i + 1)) - LEV0;
        atomicAdd(&cnt_s[li * 16 + x_sym[i]], 1);
    }
    __syncthreads();
    if (t < NLEV) {
        int run = 0;
        for (int k = 0; k < t; ++k) run += (1 << (LEV0 + k)) + 240;
        for (int s2 = 0; s2 < 16; ++s2) {
            cur_s[t * 16 + s2] = run;
            run += ((cnt_s[t * 16 + s2] + GRP - 1) / GRP) * GRP;
        }
    }
    __syncthreads();
    for (int i = lo + t; i < hi; i += 1024) {
        const int li = (31 - __clz(i + 1)) - LEV0;
        const int pos = atomicAdd(&cur_s[li * 16 + x_sym[i]], 1);
        order[pos] = i;
    }
}

__global__ __launch_bounds__(256) void level_grouped(const int* __restrict__ x_sym,
                                                     const float* __restrict__ W,
                                                     const float* __restrict__ b,
                                                     float* __restrict__ enc,
                                                     const int* __restrict__ order,
                                                     int level_off, int leaf_children) {
    const int grp  = blockIdx.x >> 2;
    const int tile = blockIdx.x & 3;
    const int base = level_off + grp * GRP;
    const int n0 = order[base];
    if (n0 < 0) return;
    const int s = x_sym[n0];
    const int t = threadIdx.x;
    const int w = t >> 6;
    const int lane = t & 63;

    __shared__ float  mean_s[GRP][MPAD];
    __shared__ float4 part_s[4][4][64];

    {
        const int c = lane << 2;
        #pragma unroll
        for (int j = 0; j < 4; ++j) {
            const int node = order[base + w * 4 + j];
            float4 m = make_float4(0.f, 0.f, 0.f, 0.f);
            if (node >= 0) {
                const int c0 = 2 * node + 1;
                if (leaf_children) {
                    const int sa = x_sym[c0], sb = x_sym[c0 + 1];
                    const float4 ba = *(const float4*)(b + sa * DIM + c);
                    const float4 bb = *(const float4*)(b + sb * DIM + c);
                    m.x = 0.5f * (tanhf(ba.x) + tanhf(bb.x));
                    m.y = 0.5f * (tanhf(ba.y) + tanhf(bb.y));
                    m.z = 0.5f * (tanhf(ba.z) + tanhf(bb.z));
                    m.w = 0.5f * (tanhf(ba.w) + tanhf(bb.w));
                } else {
                    const float4 ea = *(const float4*)(enc + (size_t)c0 * DIM + c);
                    const float4 eb = *(const float4*)(enc + (size_t)(c0 + 1) * DIM + c);
                    m.x = 0.5f * (ea.x + eb.x);
                    m.y = 0.5f * (ea.y + eb.y);
                    m.z = 0.5f * (ea.z + eb.z);
                    m.w = 0.5f * (ea.w + eb.w);
                }
            }
            *(float4*)(&mean_s[w * 4 + j][c]) = m;
        }
    }
    __syncthreads();

    const int ns4 = (lane >> 4) << 2;
    const int g4  = (lane & 15) << 2;
    const float* __restrict__ Ws =
        W + ((size_t)s << 16) + (size_t)(w * 64) * DIM + tile * 64 + g4;
    float4 acc0 = make_float4(0, 0, 0, 0), acc1 = acc0, acc2 = acc0, acc3 = acc0;
    const int dbase = w * 64;
    #pragma unroll 4
    for (int dd = 0; dd < 64; dd += 4) {
        const float4 w0 = *(const float4*)(Ws + (size_t)(dd + 0) * DIM);
        const float4 w1 = *(const float4*)(Ws + (size_t)(dd + 1) * DIM);
        const float4 w2 = *(const float4*)(Ws + (size_t)(dd + 2) * DIM);
        const float4 w3 = *(const float4*)(Ws + (size_t)(dd + 3) * DIM);
        const int d = dbase + dd;
        const float4 m0 = *(const float4*)(&mean_s[ns4 + 0][d]);
        const float4 m1 = *(const float4*)(&mean_s[ns4 + 1][d]);
        const float4 m2 = *(const float4*)(&mean_s[ns4 + 2][d]);
        const float4 m3 = *(const float4*)(&mean_s[ns4 + 3][d]);
        FMA4(acc0, m0.x, w0); FMA4(acc0, m0.y, w1); FMA4(acc0, m0.z, w2); FMA4(acc0, m0.w, w3);
        FMA4(acc1, m1.x, w0); FMA4(acc1, m1.y, w1); FMA4(acc1, m1.z, w2); FMA4(acc1, m1.w, w3);
        FMA4(acc2, m2.x, w0); FMA4(acc2, m2.y, w1); FMA4(acc2, m2.z, w2); FMA4(acc2, m2.w, w3);
        FMA4(acc3, m3.x, w0); FMA4(acc3, m3.y, w1); FMA4(acc3, m3.z, w2); FMA4(acc3, m3.w, w3);
    }
    part_s[w][0][lane] = acc0;
    part_s[w][1][lane] = acc1;
    part_s[w][2][lane] = acc2;
    part_s[w][3][lane] = acc3;
    __syncthreads();

    const int node_g = order[base + ns4 + w];
    if (node_g >= 0) {
        float4 r        = part_s[0][w][lane];
        const float4 p1 = part_s[1][w][lane];
        const float4 p2 = part_s[2][w][lane];
        const float4 p3 = part_s[3][w][lane];
        const float4 bs = *(const float4*)(b + s * DIM + tile * 64 + g4);
        r.x = tanhf(r.x + p1.x + p2.x + p3.x + bs.x);
        r.y = tanhf(r.y + p1.y + p2.y + p3.y + bs.y);
        r.z = tanhf(r.z + p1.z + p2.z + p3.z + bs.z);
        r.w = tanhf(r.w + p1.w + p2.w + p3.w + bs.w);
        *(float4*)(enc + (size_t)node_g * DIM + tile * 64 + g4) = r;
    }
}

__global__ __launch_bounds__(256) void level_small(const int* __restrict__ x_sym,
                                                   const float* __restrict__ W,
                                                   const float* __restrict__ b,
                                                   float* __restrict__ enc,
                                                   int lo, int N) {
    const int node = lo + (blockIdx.x >> 2);
    const int tile = blockIdx.x & 3;
    const int t = threadIdx.x;
    const int lane = t & 63;
    const int c = tile * 64 + lane;

    __shared__ float mean_s[DIM];
    __shared__ float part[256];

    const int s = x_sym[node];
    const int c0 = 2 * node + 1;

    float m = 0.0f;
    if (c0 < N)
        m = 0.5f * (enc[(size_t)c0 * DIM + t] + enc[(size_t)(c0 + 1) * DIM + t]);
    mean_s[t] = m;
    __syncthreads();

    float acc = 0.0f;
    if (c0 < N) {
        const float* __restrict__ Ws = W + ((size_t)s << 16);
        const int d0 = (t >> 6) * 64;
        #pragma unroll 8
        for (int d = d0; d < d0 + 64; ++d)
            acc = fmaf(mean_s[d], Ws[d * DIM + c], acc);
    }
    part[t] = acc;
    __syncthreads();

    if (t < 64) {
        float r = part[t] + part[t + 64] + part[t + 128] + part[t + 192];
        r += b[s * DIM + c];
        enc[(size_t)node * DIM + c] = tanhf(r);
    }
}

__global__ __launch_bounds__(256) void level_big(const int* __restrict__ x_sym,
                                                 const float* __restrict__ W,
                                                 const float* __restrict__ b,
                                                 float* __restrict__ enc,
                                                 int lo, int N) {
    const int node = lo + blockIdx.x;
    const int e = threadIdx.x;
    __shared__ float mean_s[DIM];
    const int s = x_sym[node];
    const int c0 = 2 * node + 1;

    float acc = b[s * DIM + e];
    if (c0 < N) {
        mean_s[e] = 0.5f * (enc[(size_t)c0 * DIM + e] + enc[(size_t)(c0 + 1) * DIM + e]);
        __syncthreads();
        const float* __restrict__ Ws = W + ((size_t)s << 16);
        #pragma unroll 8
        for (int d = 0; d < DIM; ++d)
            acc = fmaf(mean_s[d], Ws[d * DIM + e], acc);
    }
    enc[(size_t)node * DIM + e] = tanhf(acc);
}

__global__ __launch_bounds__(256) void out_kernel10(const float* __restrict__ enc,
                                                    const float* __restrict__ W_out,
                                                    const float* __restrict__ b_out,
                                                    float* __restrict__ out) {
    const int t = threadIdx.x;
    const float e = enc[t];
    float p[10];
    #pragma unroll
    for (int o = 0; o < 10; ++o) p[o] = e * W_out[t * 10 + o];
    #pragma unroll
    for (int o = 0; o < 10; ++o)
        #pragma unroll
        for (int k = 32; k >= 1; k >>= 1) p[o] += __shfl_xor(p[o], k, 64);
    __shared__ float part[4][10];
    if ((t & 63) == 0) {
        #pragma unroll
        for (int o = 0; o < 10; ++o) part[t >> 6][o] = p[o];
    }
    __syncthreads();
    if (t < 10) out[t] = b_out[t] + part[0][t] + part[1][t] + part[2][t] + part[3][t];
}

__global__ void out_kernel(const float* __restrict__ enc,
                           const float* __restrict__ W_out,
                           const float* __restrict__ b_out,
                           float* __restrict__ out, int outn) {
    const int o = threadIdx.x;
    if (o < outn) {
        float acc = b_out[o];
        for (int d = 0; d < DIM; ++d)
            acc = fmaf(enc[d], W_out[d * outn + o], acc);
        out[o] = acc;
    }
}

extern "C" void kernel_launch(void* const* d_in, const int* in_sizes, int n_in,
                              void* d_out, int out_size, void* d_ws, size_t ws_size,
                              hipStream_t stream) {
    const int*   x_sym = (const int*)d_in[0];
    const float* W     = (const float*)d_in[2];
    const float* b     = (const float*)d_in[3];
    const float* W_out = (const float*)d_in[4];
    const float* b_out = (const float*)d_in[5];
    float* out = (float*)d_out;
    float* enc = (float*)d_ws;                      // N x 256 fp32
    const int N = in_sizes[0];

    int depth = 0;
    while (((1 << depth) - 1) < N) ++depth;

    if (N == (1 << 14) - 1 && out_size == 10) {
        int* order = (int*)(enc + (size_t)N * DIM);  // 8640 ints
        int* flg   = order + 8640;                   // 8192 ints
        int* cnt   = flg + 8192;                     // 8192 ints
        int* done  = cnt + 8192;                     // 256 ints
        const size_t need = (size_t)N * DIM * 4 + (8640 + 8192 + 8192 + 256) * 4;
        if (ws_size >= need) {
            hipMemsetAsync(flg, 0, (8192 + 8192 + 256) * 4, stream);
            void* args[] = { (void*)&x_sym, (void*)&W, (void*)&b, (void*)&enc,
                             (void*)&order, (void*)&flg, (void*)&cnt, (void*)&done,
                             (void*)&W_out, (void*)&b_out, (void*)&out };
            hipError_t err = hipLaunchCooperativeKernel((const void*)fused_kernel,
                                                        dim3(NBLK), dim3(256),
                                                        args, 0, stream);
            if (err == hipSuccess) return;
            (void)hipGetLastError();   // fall through to multi-launch
        }
        sort_kernel<<<1, 1024, 0, stream>>>(x_sym, order);
        for (int d = LEV0 + NLEV - 1; d >= LEV0; --d) {
            const int li = d - LEV0;
            int off = 0;
            for (int k = 0; k < li; ++k) off += (1 << (LEV0 + k)) + 240;
            const int blocks = ((1 << d) / GRP + 15) * 4;
            level_grouped<<<blocks, 256, 0, stream>>>(x_sym, W, b, enc, order, off,
                                                      (d == depth - 2) ? 1 : 0);
        }
        for (int d = LEV0 - 1; d >= 0; --d) {
            const int lo = (1 << d) - 1;
            const int n = (1 << d);
            level_small<<<n * 4, 256, 0, stream>>>(x_sym, W, b, enc, lo, N);
        }
        out_kernel10<<<1, 256, 0, stream>>>(enc, W_out, b_out, out);
    } else {
        for (int d = depth - 1; d >= 0; --d) {
            int lo = (1 << d) - 1;
            int n = (1 << d);
            if (lo + n > N) n = N - lo;
            if (n >= 256)
                level_big<<<n, 256, 0, stream>>>(x_sym, W, b, enc, lo, N);
            else
                level_small<<<n * 4, 256, 0, stream>>>(x_sym, W, b, enc, lo, N);
        }
        out_kernel<<<1, 64, 0, stream>>>(enc, W_out, b_out, out, out_size);
    }
}

// Round 7
// 118.415 us; speedup vs baseline: 13.5571x; 1.2131x over previous
//
#include <hip/hip_runtime.h>

#define DIM 256
#define GRP 16
#define MPAD 260
#define NBLK 1024

// order[] layout (ints): level 11 @ 0 (cap 2288), level 10 @ 2288 (cap 1264),
// level 9 @ 3552 (cap 752). flg/cnt (1024 each) follow.
#define O11 0
#define O10 2288
#define O9  3552
#define OTOT 4352
#define G11_BLOCKS 572
#define G10_BLOCKS 316
#define G9_ITEMS   188

#define FMA4(a, sc, v) \
    a.x = fmaf((sc), (v).x, a.x); a.y = fmaf((sc), (v).y, a.y); \
    a.z = fmaf((sc), (v).z, a.z); a.w = fmaf((sc), (v).w, a.w);

// ---- agent-scope (LLC-coherent) ops: ONLY for flags + small tail rows ----
__device__ __forceinline__ float ld1(const float* p) {
    union { unsigned int u; float f; } cv;
    cv.u = __hip_atomic_load((const unsigned int*)p, __ATOMIC_RELAXED,
                             __HIP_MEMORY_SCOPE_AGENT);
    return cv.f;
}
__device__ __forceinline__ void st1f(float* p, float x) {
    union { unsigned int u; float f; } cv; cv.f = x;
    __hip_atomic_store((unsigned int*)p, cv.u, __ATOMIC_RELAXED,
                       __HIP_MEMORY_SCOPE_AGENT);
}
__device__ __forceinline__ void st2(float* p, float x, float y) {
    union { unsigned long long u; float2 f; } cv;
    cv.f = make_float2(x, y);
    __hip_atomic_store((unsigned long long*)p, cv.u, __ATOMIC_RELAXED,
                       __HIP_MEMORY_SCOPE_AGENT);
}
__device__ __forceinline__ int addi(int* p) {
    return __hip_atomic_fetch_add(p, 1, __ATOMIC_RELAXED, __HIP_MEMORY_SCOPE_AGENT);
}
__device__ __forceinline__ void sti(int* p, int v) {
    __hip_atomic_store(p, v, __ATOMIC_RELAXED, __HIP_MEMORY_SCOPE_AGENT);
}
__device__ __forceinline__ void spin(const int* f) {
    int guard = 0;
    while (__hip_atomic_load(f, __ATOMIC_RELAXED, __HIP_MEMORY_SCOPE_AGENT) == 0) {
        __builtin_amdgcn_s_sleep(1);
        if (++guard > (1 << 20)) break;   // never hard-hang the harness
    }
}

// shared 16-node x 64-col FMA core. Ws pre-offset by s, K-chunk, tile, g4.
__device__ __forceinline__ void gemm_core(const float* __restrict__ Ws,
                                          const float mean_s[GRP][MPAD],
                                          float4 part_s[4][4][64],
                                          int w, int lane) {
    const int ns4 = (lane >> 4) << 2;
    float4 acc0 = make_float4(0, 0, 0, 0), acc1 = acc0, acc2 = acc0, acc3 = acc0;
    const int dbase = w * 64;
    #pragma unroll 4
    for (int dd = 0; dd < 64; dd += 4) {
        const float4 w0 = *(const float4*)(Ws + (size_t)(dd + 0) * DIM);
        const float4 w1 = *(const float4*)(Ws + (size_t)(dd + 1) * DIM);
        const float4 w2 = *(const float4*)(Ws + (size_t)(dd + 2) * DIM);
        const float4 w3 = *(const float4*)(Ws + (size_t)(dd + 3) * DIM);
        const int dk = dbase + dd;
        const float4 m0 = *(const float4*)(&mean_s[ns4 + 0][dk]);
        const float4 m1 = *(const float4*)(&mean_s[ns4 + 1][dk]);
        const float4 m2 = *(const float4*)(&mean_s[ns4 + 2][dk]);
        const float4 m3 = *(const float4*)(&mean_s[ns4 + 3][dk]);
        FMA4(acc0, m0.x, w0); FMA4(acc0, m0.y, w1); FMA4(acc0, m0.z, w2); FMA4(acc0, m0.w, w3);
        FMA4(acc1, m1.x, w0); FMA4(acc1, m1.y, w1); FMA4(acc1, m1.z, w2); FMA4(acc1, m1.w, w3);
        FMA4(acc2, m2.x, w0); FMA4(acc2, m2.y, w1); FMA4(acc2, m2.z, w2); FMA4(acc2, m2.w, w3);
        FMA4(acc3, m3.x, w0); FMA4(acc3, m3.y, w1); FMA4(acc3, m3.z, w2); FMA4(acc3, m3.w, w3);
    }
    part_s[w][0][lane] = acc0;
    part_s[w][1][lane] = acc1;
    part_s[w][2][lane] = acc2;
    part_s[w][3][lane] = acc3;
}

__device__ __forceinline__ void unpair(int p, int& pa, int& pb) {
    int a = 0, rem = p;
    while (rem >= 16 - a) { rem -= 16 - a; ++a; }
    pa = a; pb = a + rem;
}

// ===== launch 1: combo table (level 12 memoized) + 3-level sort + flag zero =====
__global__ __launch_bounds__(256) void combo_sort_zero(const int* __restrict__ x_sym,
                                                       const float* __restrict__ W,
                                                       const float* __restrict__ b,
                                                       float* __restrict__ T,
                                                       int* __restrict__ order,
                                                       int* __restrict__ flg) {
    __shared__ float  mean_s[GRP][MPAD];
    __shared__ float4 part_s[4][4][64];
    __shared__ int cnt_s[16], cur_s[16];
    const int t = threadIdx.x;
    const int w = t >> 6;
    const int lane = t & 63;
    const int bid = blockIdx.x;

    if (bid < 576) {  // ---- combo: T[s][pa][pb] for all pa<=pb, symmetric fill ----
        const int s = bid / 36;
        const int rem = bid % 36;
        const int chunk = rem >> 2;
        const int tile = rem & 3;
        {
            const int c = lane << 2;
            #pragma unroll
            for (int j = 0; j < 4; ++j) {
                const int p = chunk * 16 + w * 4 + j;
                float4 m = make_float4(0.f, 0.f, 0.f, 0.f);
                if (p < 136) {
                    int pa, pb; unpair(p, pa, pb);
                    const float4 ba = *(const float4*)(b + pa * DIM + c);
                    const float4 bb = *(const float4*)(b + pb * DIM + c);
                    m.x = 0.5f * (tanhf(ba.x) + tanhf(bb.x));
                    m.y = 0.5f * (tanhf(ba.y) + tanhf(bb.y));
                    m.z = 0.5f * (tanhf(ba.z) + tanhf(bb.z));
                    m.w = 0.5f * (tanhf(ba.w) + tanhf(bb.w));
                }
                *(float4*)(&mean_s[w * 4 + j][c]) = m;
            }
        }
        __syncthreads();
        const int ns4 = (lane >> 4) << 2;
        const int g4  = (lane & 15) << 2;
        gemm_core(W + ((size_t)s << 16) + (size_t)(w * 64) * DIM + tile * 64 + g4,
                  mean_s, part_s, w, lane);
        __syncthreads();
        const int p = chunk * 16 + ns4 + w;
        if (p < 136) {
            int pa, pb; unpair(p, pa, pb);
            float4 r        = part_s[0][w][lane];
            const float4 p1 = part_s[1][w][lane];
            const float4 p2 = part_s[2][w][lane];
            const float4 p3 = part_s[3][w][lane];
            const float4 bs = *(const float4*)(b + s * DIM + tile * 64 + g4);
            r.x = tanhf(r.x + p1.x + p2.x + p3.x + bs.x);
            r.y = tanhf(r.y + p1.y + p2.y + p3.y + bs.y);
            r.z = tanhf(r.z + p1.z + p2.z + p3.z + bs.z);
            r.w = tanhf(r.w + p1.w + p2.w + p3.w + bs.w);
            *(float4*)(T + (size_t)((s * 16 + pa) * 16 + pb) * DIM + tile * 64 + g4) = r;
            if (pa != pb)
                *(float4*)(T + (size_t)((s * 16 + pb) * 16 + pa) * DIM + tile * 64 + g4) = r;
        }
    } else if (bid == 576) {  // ---- sort levels 11,10,9 by symbol ----
        const int offs[3] = {O11, O10, O9};
        for (int li = 0; li < 3; ++li) {
            const int d = 11 - li;
            const int off = offs[li];
            const int lo = (1 << d) - 1;
            const int n = 1 << d;
            for (int i = t; i < n + 240; i += 256) order[off + i] = -1;
            if (t < 16) cnt_s[t] = 0;
            __syncthreads();
            for (int i = t; i < n; i += 256) atomicAdd(&cnt_s[x_sym[lo + i]], 1);
            __syncthreads();
            if (t == 0) {
                int run = off;
                for (int s2 = 0; s2 < 16; ++s2) {
                    cur_s[s2] = run;
                    run += ((cnt_s[s2] + GRP - 1) / GRP) * GRP;
                }
            }
            __syncthreads();
            for (int i = t; i < n; i += 256) {
                const int pos = atomicAdd(&cur_s[x_sym[lo + i]], 1);
                order[pos] = lo + i;
            }
            __syncthreads();
        }
    } else {  // ---- bid 577: zero flg + cnt (2048 ints) ----
        for (int i = t; i < 2048; i += 256) flg[i] = 0;
    }
}

// ===== launch 2: level 11, staging via combo table lookup =====
__global__ __launch_bounds__(256) void grouped_T(const int* __restrict__ x_sym,
                                                 const float* __restrict__ W,
                                                 const float* __restrict__ b,
                                                 float* __restrict__ enc,
                                                 const float* __restrict__ T,
                                                 const int* __restrict__ order) {
    const int base = (blockIdx.x >> 2) * GRP + O11;
    const int tile = blockIdx.x & 3;
    const int n0 = order[base];
    if (n0 < 0) return;
    const int s = x_sym[n0];
    const int t = threadIdx.x;
    const int w = t >> 6;
    const int lane = t & 63;
    __shared__ float  mean_s[GRP][MPAD];
    __shared__ float4 part_s[4][4][64];
    {
        const int c = lane << 2;
        #pragma unroll
        for (int j = 0; j < 4; ++j) {
            const int node = order[base + w * 4 + j];
            float4 m = make_float4(0.f, 0.f, 0.f, 0.f);
            if (node >= 0) {
                const int c0 = 2 * node + 1, c1 = c0 + 1;
                const float* r0 = T + (size_t)((x_sym[c0] * 16 + x_sym[2 * c0 + 1]) * 16
                                               + x_sym[2 * c0 + 2]) * DIM;
                const float* r1 = T + (size_t)((x_sym[c1] * 16 + x_sym[2 * c1 + 1]) * 16
                                               + x_sym[2 * c1 + 2]) * DIM;
                const float4 ea = *(const float4*)(r0 + c);
                const float4 eb = *(const float4*)(r1 + c);
                m.x = 0.5f * (ea.x + eb.x);
                m.y = 0.5f * (ea.y + eb.y);
                m.z = 0.5f * (ea.z + eb.z);
                m.w = 0.5f * (ea.w + eb.w);
            }
            *(float4*)(&mean_s[w * 4 + j][c]) = m;
        }
    }
    __syncthreads();
    const int ns4 = (lane >> 4) << 2;
    const int g4  = (lane & 15) << 2;
    gemm_core(W + ((size_t)s << 16) + (size_t)(w * 64) * DIM + tile * 64 + g4,
              mean_s, part_s, w, lane);
    __syncthreads();
    const int node_g = order[base + ns4 + w];
    if (node_g >= 0) {
        float4 r        = part_s[0][w][lane];
        const float4 p1 = part_s[1][w][lane];
        const float4 p2 = part_s[2][w][lane];
        const float4 p3 = part_s[3][w][lane];
        const float4 bs = *(const float4*)(b + s * DIM + tile * 64 + g4);
        r.x = tanhf(r.x + p1.x + p2.x + p3.x + bs.x);
        r.y = tanhf(r.y + p1.y + p2.y + p3.y + bs.y);
        r.z = tanhf(r.z + p1.z + p2.z + p3.z + bs.z);
        r.w = tanhf(r.w + p1.w + p2.w + p3.w + bs.w);
        *(float4*)(enc + (size_t)node_g * DIM + tile * 64 + g4) = r;
    }
}

// ===== launch 3 (and fallbacks): grouped level reading enc =====
__global__ __launch_bounds__(256) void grouped_enc(const int* __restrict__ x_sym,
                                                   const float* __restrict__ W,
                                                   const float* __restrict__ b,
                                                   float* __restrict__ enc,
                                                   const int* __restrict__ order,
                                                   int level_off) {
    const int base = (blockIdx.x >> 2) * GRP + level_off;
    const int tile = blockIdx.x & 3;
    const int n0 = order[base];
    if (n0 < 0) return;
    const int s = x_sym[n0];
    const int t = threadIdx.x;
    const int w = t >> 6;
    const int lane = t & 63;
    __shared__ float  mean_s[GRP][MPAD];
    __shared__ float4 part_s[4][4][64];
    {
        const int c = lane << 2;
        #pragma unroll
        for (int j = 0; j < 4; ++j) {
            const int node = order[base + w * 4 + j];
            float4 m = make_float4(0.f, 0.f, 0.f, 0.f);
            if (node >= 0) {
                const int c0 = 2 * node + 1;
                const float4 ea = *(const float4*)(enc + (size_t)c0 * DIM + c);
                const float4 eb = *(const float4*)(enc + (size_t)(c0 + 1) * DIM + c);
                m.x = 0.5f * (ea.x + eb.x);
                m.y = 0.5f * (ea.y + eb.y);
                m.z = 0.5f * (ea.z + eb.z);
                m.w = 0.5f * (ea.w + eb.w);
            }
            *(float4*)(&mean_s[w * 4 + j][c]) = m;
        }
    }
    __syncthreads();
    const int ns4 = (lane >> 4) << 2;
    const int g4  = (lane & 15) << 2;
    gemm_core(W + ((size_t)s << 16) + (size_t)(w * 64) * DIM + tile * 64 + g4,
              mean_s, part_s, w, lane);
    __syncthreads();
    const int node_g = order[base + ns4 + w];
    if (node_g >= 0) {
        float4 r        = part_s[0][w][lane];
        const float4 p1 = part_s[1][w][lane];
        const float4 p2 = part_s[2][w][lane];
        const float4 p3 = part_s[3][w][lane];
        const float4 bs = *(const float4*)(b + s * DIM + tile * 64 + g4);
        r.x = tanhf(r.x + p1.x + p2.x + p3.x + bs.x);
        r.y = tanhf(r.y + p1.y + p2.y + p3.y + bs.y);
        r.z = tanhf(r.z + p1.z + p2.z + p3.z + bs.z);
        r.w = tanhf(r.w + p1.w + p2.w + p3.w + bs.w);
        *(float4*)(enc + (size_t)node_g * DIM + tile * 64 + g4) = r;
    }
}

// ===== launch 4: grouped level 9 + flag-chained levels 8..0 + head =====
__global__ __launch_bounds__(256, 4) void tail_kernel(const int* __restrict__ x_sym,
                                                      const float* __restrict__ W,
                                                      const float* __restrict__ b,
                                                      float* __restrict__ enc,
                                                      const int* __restrict__ order,
                                                      int* __restrict__ flg,
                                                      int* __restrict__ cnt,
                                                      const float* __restrict__ W_out,
                                                      const float* __restrict__ b_out,
                                                      float* __restrict__ out) {
    __shared__ float  mean_s[GRP][MPAD];
    __shared__ float4 part_s[4][4][64];
    const int t = threadIdx.x;
    const int w = t >> 6;
    const int lane = t & 63;
    const int bid = blockIdx.x;

    // ---- phase 1: grouped level 9 (children = level-10 enc, cached reads) ----
    if (bid < G9_ITEMS) {
        const int base = (bid >> 2) * GRP + O9;
        const int tile = bid & 3;
        const int n0 = order[base];
        if (n0 >= 0) {
            const int s = x_sym[n0];
            const int c = lane << 2;
            #pragma unroll
            for (int j = 0; j < 4; ++j) {
                const int node = order[base + w * 4 + j];
                float4 m = make_float4(0.f, 0.f, 0.f, 0.f);
                if (node >= 0) {
                    const int c0 = 2 * node + 1;
                    const float4 ea = *(const float4*)(enc + (size_t)c0 * DIM + c);
                    const float4 eb = *(const float4*)(enc + (size_t)(c0 + 1) * DIM + c);
                    m.x = 0.5f * (ea.x + eb.x);
                    m.y = 0.5f * (ea.y + eb.y);
                    m.z = 0.5f * (ea.z + eb.z);
                    m.w = 0.5f * (ea.w + eb.w);
                }
                *(float4*)(&mean_s[w * 4 + j][c]) = m;
            }
            __syncthreads();
            const int ns4 = (lane >> 4) << 2;
            const int g4  = (lane & 15) << 2;
            gemm_core(W + ((size_t)s << 16) + (size_t)(w * 64) * DIM + tile * 64 + g4,
                      mean_s, part_s, w, lane);
            __syncthreads();
            const int node_g = order[base + ns4 + w];
            if (node_g >= 0) {
                float4 r        = part_s[0][w][lane];
                const float4 p1 = part_s[1][w][lane];
                const float4 p2 = part_s[2][w][lane];
                const float4 p3 = part_s[3][w][lane];
                const float4 bs = *(const float4*)(b + s * DIM + tile * 64 + g4);
                r.x = tanhf(r.x + p1.x + p2.x + p3.x + bs.x);
                r.y = tanhf(r.y + p1.y + p2.y + p3.y + bs.y);
                r.z = tanhf(r.z + p1.z + p2.z + p3.z + bs.z);
                r.w = tanhf(r.w + p1.w + p2.w + p3.w + bs.w);
                float* ep = enc + (size_t)node_g * DIM + tile * 64 + g4;
                st2(ep, r.x, r.y);
                st2(ep + 2, r.z, r.w);
            }
            __syncthreads();   // drain enc stores (vmcnt 0) before flagging
            if (t < 16) {
                const int ng = order[base + t];
                if (ng >= 0 && addi(&cnt[ng]) == 3) sti(&flg[ng], 1);
            }
        }
        __syncthreads();
    }

    // ---- phase 2: levels 8..0, flag-chained; 4 col-tile blocks per node ----
    float* smean = (float*)&mean_s[0][0];
    float* spart = (float*)&part_s[0][0][0];
    for (int d = 8; d >= 0; --d) {
        const int items = 4 << d;
        if (bid >= items) return;   // retire
        const int node = (1 << d) - 1 + (bid >> 2);
        const int tile = bid & 3;
        const int c0 = 2 * node + 1;
        const int cc = tile * 64 + lane;
        if (t < 2) spin(&flg[c0 + t]);
        __syncthreads();
        const int s = x_sym[node];
        smean[t] = 0.5f * (ld1(enc + (size_t)c0 * DIM + t) +
                           ld1(enc + (size_t)(c0 + 1) * DIM + t));
        __syncthreads();
        float acc = 0.0f;
        const float* __restrict__ Ws = W + ((size_t)s << 16);
        const int d0 = w * 64;
        #pragma unroll 8
        for (int k = d0; k < d0 + 64; ++k)
            acc = fmaf(smean[k], Ws[(size_t)k * DIM + cc], acc);
        spart[t] = acc;
        __syncthreads();
        if (t < 64) {
            float r = spart[t] + spart[t + 64] + spart[t + 128] + spart[t + 192];
            r += b[s * DIM + tile * 64 + t];
            st1f(enc + (size_t)node * DIM + tile * 64 + t, tanhf(r));
        }
        __syncthreads();   // drain stores before flag
        if (t == 0 && addi(&cnt[node]) == 3) sti(&flg[node], 1);
        __syncthreads();   // LDS reuse guard
    }

    // ---- head: block 0 ----
    if (bid == 0) {
        if (t == 0) spin(&flg[0]);
        __syncthreads();
        const float e = ld1(enc + t);
        float p[10];
        #pragma unroll
        for (int o = 0; o < 10; ++o) p[o] = e * W_out[t * 10 + o];
        #pragma unroll
        for (int o = 0; o < 10; ++o)
            #pragma unroll
            for (int k = 32; k >= 1; k >>= 1) p[o] += __shfl_xor(p[o], k, 64);
        float* hp = (float*)&part_s[0][0][0];
        if (lane == 0) {
            #pragma unroll
            for (int o = 0; o < 10; ++o) hp[w * 10 + o] = p[o];
        }
        __syncthreads();
        if (t < 10) out[t] = b_out[t] + hp[t] + hp[10 + t] + hp[20 + t] + hp[30 + t];
    }
}

// ======================= generic / coop-fail fallbacks =======================
__global__ __launch_bounds__(256) void level_small(const int* __restrict__ x_sym,
                                                   const float* __restrict__ W,
                                                   const float* __restrict__ b,
                                                   float* __restrict__ enc,
                                                   int lo, int N) {
    const int node = lo + (blockIdx.x >> 2);
    const int tile = blockIdx.x & 3;
    const int t = threadIdx.x;
    const int lane = t & 63;
    const int c = tile * 64 + lane;
    __shared__ float mean_s[DIM];
    __shared__ float part[256];
    const int s = x_sym[node];
    const int c0 = 2 * node + 1;
    float m = 0.0f;
    if (c0 < N)
        m = 0.5f * (enc[(size_t)c0 * DIM + t] + enc[(size_t)(c0 + 1) * DIM + t]);
    mean_s[t] = m;
    __syncthreads();
    float acc = 0.0f;
    if (c0 < N) {
        const float* __restrict__ Ws = W + ((size_t)s << 16);
        const int d0 = (t >> 6) * 64;
        #pragma unroll 8
        for (int d = d0; d < d0 + 64; ++d)
            acc = fmaf(mean_s[d], Ws[d * DIM + c], acc);
    }
    part[t] = acc;
    __syncthreads();
    if (t < 64) {
        float r = part[t] + part[t + 64] + part[t + 128] + part[t + 192];
        r += b[s * DIM + c];
        enc[(size_t)node * DIM + c] = tanhf(r);
    }
}

__global__ __launch_bounds__(256) void level_big(const int* __restrict__ x_sym,
                                                 const float* __restrict__ W,
                                                 const float* __restrict__ b,
                                                 float* __restrict__ enc,
                                                 int lo, int N) {
    const int node = lo + blockIdx.x;
    const int e = threadIdx.x;
    __shared__ float mean_s[DIM];
    const int s = x_sym[node];
    const int c0 = 2 * node + 1;
    float acc = b[s * DIM + e];
    if (c0 < N) {
        mean_s[e] = 0.5f * (enc[(size_t)c0 * DIM + e] + enc[(size_t)(c0 + 1) * DIM + e]);
        __syncthreads();
        const float* __restrict__ Ws = W + ((size_t)s << 16);
        #pragma unroll 8
        for (int d = 0; d < DIM; ++d)
            acc = fmaf(mean_s[d], Ws[d * DIM + e], acc);
    }
    enc[(size_t)node * DIM + e] = tanhf(acc);
}

__global__ __launch_bounds__(256) void out_kernel10(const float* __restrict__ enc,
                                                    const float* __restrict__ W_out,
                                                    const float* __restrict__ b_out,
                                                    float* __restrict__ out) {
    const int t = threadIdx.x;
    const float e = enc[t];
    float p[10];
    #pragma unroll
    for (int o = 0; o < 10; ++o) p[o] = e * W_out[t * 10 + o];
    #pragma unroll
    for (int o = 0; o < 10; ++o)
        #pragma unroll
        for (int k = 32; k >= 1; k >>= 1) p[o] += __shfl_xor(p[o], k, 64);
    __shared__ float part[4][10];
    if ((t & 63) == 0) {
        #pragma unroll
        for (int o = 0; o < 10; ++o) part[t >> 6][o] = p[o];
    }
    __syncthreads();
    if (t < 10) out[t] = b_out[t] + part[0][t] + part[1][t] + part[2][t] + part[3][t];
}

__global__ void out_kernel(const float* __restrict__ enc,
                           const float* __restrict__ W_out,
                           const float* __restrict__ b_out,
                           float* __restrict__ out, int outn) {
    const int o = threadIdx.x;
    if (o < outn) {
        float acc = b_out[o];
        for (int d = 0; d < DIM; ++d)
            acc = fmaf(enc[d], W_out[d * outn + o], acc);
        out[o] = acc;
    }
}

extern "C" void kernel_launch(void* const* d_in, const int* in_sizes, int n_in,
                              void* d_out, int out_size, void* d_ws, size_t ws_size,
                              hipStream_t stream) {
    const int*   x_sym = (const int*)d_in[0];
    const float* W     = (const float*)d_in[2];
    const float* b     = (const float*)d_in[3];
    const float* W_out = (const float*)d_in[4];
    const float* b_out = (const float*)d_in[5];
    float* out = (float*)d_out;
    float* enc = (float*)d_ws;                      // N x 256 fp32
    const int N = in_sizes[0];

    int depth = 0;
    while (((1 << depth) - 1) < N) ++depth;

    const size_t need = (size_t)16383 * DIM * 4 + (OTOT + 2048) * 4;
    if (N == (1 << 14) - 1 && out_size == 10 && ws_size >= need) {
        float* T   = enc + (size_t)8191 * DIM;       // combo table in unused leaf rows
        int* order = (int*)(enc + (size_t)N * DIM);  // OTOT ints
        int* flg   = order + OTOT;                   // 1024
        int* cnt   = flg + 1024;                     // 1024

        combo_sort_zero<<<578, 256, 0, stream>>>(x_sym, W, b, T, order, flg);
        grouped_T<<<G11_BLOCKS, 256, 0, stream>>>(x_sym, W, b, enc, T, order);
        grouped_enc<<<G10_BLOCKS, 256, 0, stream>>>(x_sym, W, b, enc, order, O10);

        void* args[] = { (void*)&x_sym, (void*)&W, (void*)&b, (void*)&enc,
                         (void*)&order, (void*)&flg, (void*)&cnt,
                         (void*)&W_out, (void*)&b_out, (void*)&out };
        hipError_t err = hipLaunchCooperativeKernel((const void*)tail_kernel,
                                                    dim3(NBLK), dim3(256),
                                                    args, 0, stream);
        if (err == hipSuccess) return;
        (void)hipGetLastError();
        // coop failed: finish with proven multi-launch (level 9 .. head)
        grouped_enc<<<G9_ITEMS, 256, 0, stream>>>(x_sym, W, b, enc, order, O9);
        for (int d = 8; d >= 0; --d)
            level_small<<<(1 << d) * 4, 256, 0, stream>>>(x_sym, W, b, enc,
                                                          (1 << d) - 1, N);
        out_kernel10<<<1, 256, 0, stream>>>(enc, W_out, b_out, out);
    } else {
        for (int d = depth - 1; d >= 0; --d) {
            int lo = (1 << d) - 1;
            int n = (1 << d);
            if (lo + n > N) n = N - lo;
            if (n >= 256)
                level_big<<<n, 256, 0, stream>>>(x_sym, W, b, enc, lo, N);
            else
                level_small<<<n * 4, 256, 0, stream>>>(x_sym, W, b, enc, lo, N);
        }
        out_kernel<<<1, 64, 0, stream>>>(enc, W_out, b_out, out, out_size);
    }
}

// Round 8
// 117.489 us; speedup vs baseline: 13.6639x; 1.0079x over previous
//
#include <hip/hip_runtime.h>

#define DIM 256
#define GRP 16
#define MPAD 260
#define NBLK 1024

// order[] layout (ints): level 11 @ 0 (cap 2288), level 10 @ 2288 (cap 1264),
// level 9 @ 3552 (cap 752). cnt (1024 ints) follows.
#define O11 0
#define O10 2288
#define O9  3552
#define OTOT 4352
#define G11_BLOCKS 572
#define G10_BLOCKS 316
#define G9_ITEMS   188

#define FMA4(a, sc, v) \
    a.x = fmaf((sc), (v).x, a.x); a.y = fmaf((sc), (v).y, a.y); \
    a.z = fmaf((sc), (v).z, a.z); a.w = fmaf((sc), (v).w, a.w);

// ---- agent-scope (LLC-coherent) ops: flags + small tail rows only ----
__device__ __forceinline__ float ld1(const float* p) {
    union { unsigned int u; float f; } cv;
    cv.u = __hip_atomic_load((const unsigned int*)p, __ATOMIC_RELAXED,
                             __HIP_MEMORY_SCOPE_AGENT);
    return cv.f;
}
__device__ __forceinline__ float2 ld2(const float* p) {
    union { unsigned long long u; float2 f; } cv;
    cv.u = __hip_atomic_load((const unsigned long long*)p, __ATOMIC_RELAXED,
                             __HIP_MEMORY_SCOPE_AGENT);
    return cv.f;
}
__device__ __forceinline__ void st1f(float* p, float x) {
    union { unsigned int u; float f; } cv; cv.f = x;
    __hip_atomic_store((unsigned int*)p, cv.u, __ATOMIC_RELAXED,
                       __HIP_MEMORY_SCOPE_AGENT);
}
__device__ __forceinline__ void st2(float* p, float x, float y) {
    union { unsigned long long u; float2 f; } cv;
    cv.f = make_float2(x, y);
    __hip_atomic_store((unsigned long long*)p, cv.u, __ATOMIC_RELAXED,
                       __HIP_MEMORY_SCOPE_AGENT);
}
__device__ __forceinline__ int addi(int* p) {
    return __hip_atomic_fetch_add(p, 1, __ATOMIC_RELAXED, __HIP_MEMORY_SCOPE_AGENT);
}
__device__ __forceinline__ void spin4(const int* f) {
    if (__hip_atomic_load(f, __ATOMIC_RELAXED, __HIP_MEMORY_SCOPE_AGENT) >= 4) return;
    int guard = 0;
    do {
        __builtin_amdgcn_s_sleep(1);
        if (++guard > (1 << 19)) break;   // never hard-hang the harness
    } while (__hip_atomic_load(f, __ATOMIC_RELAXED, __HIP_MEMORY_SCOPE_AGENT) < 4);
}

// shared 16-node x 64-col FMA core. Ws pre-offset by s, K-chunk, tile, g4.
__device__ __forceinline__ void gemm_core(const float* __restrict__ Ws,
                                          const float mean_s[GRP][MPAD],
                                          float4 part_s[4][4][64],
                                          int w, int lane) {
    const int ns4 = (lane >> 4) << 2;
    float4 acc0 = make_float4(0, 0, 0, 0), acc1 = acc0, acc2 = acc0, acc3 = acc0;
    const int dbase = w * 64;
    #pragma unroll 4
    for (int dd = 0; dd < 64; dd += 4) {
        const float4 w0 = *(const float4*)(Ws + (size_t)(dd + 0) * DIM);
        const float4 w1 = *(const float4*)(Ws + (size_t)(dd + 1) * DIM);
        const float4 w2 = *(const float4*)(Ws + (size_t)(dd + 2) * DIM);
        const float4 w3 = *(const float4*)(Ws + (size_t)(dd + 3) * DIM);
        const int dk = dbase + dd;
        const float4 m0 = *(const float4*)(&mean_s[ns4 + 0][dk]);
        const float4 m1 = *(const float4*)(&mean_s[ns4 + 1][dk]);
        const float4 m2 = *(const float4*)(&mean_s[ns4 + 2][dk]);
        const float4 m3 = *(const float4*)(&mean_s[ns4 + 3][dk]);
        FMA4(acc0, m0.x, w0); FMA4(acc0, m0.y, w1); FMA4(acc0, m0.z, w2); FMA4(acc0, m0.w, w3);
        FMA4(acc1, m1.x, w0); FMA4(acc1, m1.y, w1); FMA4(acc1, m1.z, w2); FMA4(acc1, m1.w, w3);
        FMA4(acc2, m2.x, w0); FMA4(acc2, m2.y, w1); FMA4(acc2, m2.z, w2); FMA4(acc2, m2.w, w3);
        FMA4(acc3, m3.x, w0); FMA4(acc3, m3.y, w1); FMA4(acc3, m3.z, w2); FMA4(acc3, m3.w, w3);
    }
    part_s[w][0][lane] = acc0;
    part_s[w][1][lane] = acc1;
    part_s[w][2][lane] = acc2;
    part_s[w][3][lane] = acc3;
}

__device__ __forceinline__ void unpair(int p, int& pa, int& pb) {
    int a = 0, rem = p;
    while (rem >= 16 - a) { rem -= 16 - a; ++a; }
    pa = a; pb = a + rem;
}

// ===== launch 1: combo table (level 12 memoized) + 3 parallel sorts + cnt zero =====
__global__ __launch_bounds__(256) void combo_sort_zero(const int* __restrict__ x_sym,
                                                       const float* __restrict__ W,
                                                       const float* __restrict__ b,
                                                       float* __restrict__ T,
                                                       int* __restrict__ order,
                                                       int* __restrict__ cnt) {
    __shared__ float  mean_s[GRP][MPAD];
    __shared__ float4 part_s[4][4][64];
    __shared__ int cnt_s[16], cur_s[16];
    const int t = threadIdx.x;
    const int w = t >> 6;
    const int lane = t & 63;
    const int bid = blockIdx.x;

    if (bid < 576) {  // ---- combo: T[s][pa][pb] for all pa<=pb, symmetric fill ----
        const int s = bid / 36;
        const int rem = bid % 36;
        const int chunk = rem >> 2;
        const int tile = rem & 3;
        {
            const int c = lane << 2;
            #pragma unroll
            for (int j = 0; j < 4; ++j) {
                const int p = chunk * 16 + w * 4 + j;
                float4 m = make_float4(0.f, 0.f, 0.f, 0.f);
                if (p < 136) {
                    int pa, pb; unpair(p, pa, pb);
                    const float4 ba = *(const float4*)(b + pa * DIM + c);
                    const float4 bb = *(const float4*)(b + pb * DIM + c);
                    m.x = 0.5f * (tanhf(ba.x) + tanhf(bb.x));
                    m.y = 0.5f * (tanhf(ba.y) + tanhf(bb.y));
                    m.z = 0.5f * (tanhf(ba.z) + tanhf(bb.z));
                    m.w = 0.5f * (tanhf(ba.w) + tanhf(bb.w));
                }
                *(float4*)(&mean_s[w * 4 + j][c]) = m;
            }
        }
        __syncthreads();
        const int ns4 = (lane >> 4) << 2;
        const int g4  = (lane & 15) << 2;
        gemm_core(W + ((size_t)s << 16) + (size_t)(w * 64) * DIM + tile * 64 + g4,
                  mean_s, part_s, w, lane);
        __syncthreads();
        const int p = chunk * 16 + ns4 + w;
        if (p < 136) {
            int pa, pb; unpair(p, pa, pb);
            float4 r        = part_s[0][w][lane];
            const float4 p1 = part_s[1][w][lane];
            const float4 p2 = part_s[2][w][lane];
            const float4 p3 = part_s[3][w][lane];
            const float4 bs = *(const float4*)(b + s * DIM + tile * 64 + g4);
            r.x = tanhf(r.x + p1.x + p2.x + p3.x + bs.x);
            r.y = tanhf(r.y + p1.y + p2.y + p3.y + bs.y);
            r.z = tanhf(r.z + p1.z + p2.z + p3.z + bs.z);
            r.w = tanhf(r.w + p1.w + p2.w + p3.w + bs.w);
            *(float4*)(T + (size_t)((s * 16 + pa) * 16 + pb) * DIM + tile * 64 + g4) = r;
            if (pa != pb)
                *(float4*)(T + (size_t)((s * 16 + pb) * 16 + pa) * DIM + tile * 64 + g4) = r;
        }
    } else if (bid <= 578) {  // ---- 3 parallel sorts: levels 11, 10, 9 ----
        const int li = bid - 576;
        const int d = 11 - li;
        const int off = (li == 0) ? O11 : (li == 1) ? O10 : O9;
        const int lo = (1 << d) - 1;
        const int n = 1 << d;
        for (int i = t; i < n + 240; i += 256) order[off + i] = -1;
        if (t < 16) cnt_s[t] = 0;
        __syncthreads();
        for (int i = t; i < n; i += 256) atomicAdd(&cnt_s[x_sym[lo + i]], 1);
        __syncthreads();
        if (t == 0) {
            int run = off;
            for (int s2 = 0; s2 < 16; ++s2) {
                cur_s[s2] = run;
                run += ((cnt_s[s2] + GRP - 1) / GRP) * GRP;
            }
        }
        __syncthreads();
        for (int i = t; i < n; i += 256) {
            const int pos = atomicAdd(&cur_s[x_sym[lo + i]], 1);
            order[pos] = lo + i;
        }
    } else {  // ---- bid 579: zero cnt (1024 ints); visible at LLC after launch ends ----
        for (int i = t; i < 1024; i += 256) cnt[i] = 0;
    }
}

// ===== launch 2: level 11, staging via combo table lookup =====
__global__ __launch_bounds__(256) void grouped_T(const int* __restrict__ x_sym,
                                                 const float* __restrict__ W,
                                                 const float* __restrict__ b,
                                                 float* __restrict__ enc,
                                                 const float* __restrict__ T,
                                                 const int* __restrict__ order) {
    const int base = (blockIdx.x >> 2) * GRP + O11;
    const int tile = blockIdx.x & 3;
    const int n0 = order[base];
    if (n0 < 0) return;
    const int s = x_sym[n0];
    const int t = threadIdx.x;
    const int w = t >> 6;
    const int lane = t & 63;
    __shared__ float  mean_s[GRP][MPAD];
    __shared__ float4 part_s[4][4][64];
    {
        const int c = lane << 2;
        #pragma unroll
        for (int j = 0; j < 4; ++j) {
            const int node = order[base + w * 4 + j];
            float4 m = make_float4(0.f, 0.f, 0.f, 0.f);
            if (node >= 0) {
                const int c0 = 2 * node + 1, c1 = c0 + 1;
                const float* r0 = T + (size_t)((x_sym[c0] * 16 + x_sym[2 * c0 + 1]) * 16
                                               + x_sym[2 * c0 + 2]) * DIM;
                const float* r1 = T + (size_t)((x_sym[c1] * 16 + x_sym[2 * c1 + 1]) * 16
                                               + x_sym[2 * c1 + 2]) * DIM;
                const float4 ea = *(const float4*)(r0 + c);
                const float4 eb = *(const float4*)(r1 + c);
                m.x = 0.5f * (ea.x + eb.x);
                m.y = 0.5f * (ea.y + eb.y);
                m.z = 0.5f * (ea.z + eb.z);
                m.w = 0.5f * (ea.w + eb.w);
            }
            *(float4*)(&mean_s[w * 4 + j][c]) = m;
        }
    }
    __syncthreads();
    const int ns4 = (lane >> 4) << 2;
    const int g4  = (lane & 15) << 2;
    gemm_core(W + ((size_t)s << 16) + (size_t)(w * 64) * DIM + tile * 64 + g4,
              mean_s, part_s, w, lane);
    __syncthreads();
    const int node_g = order[base + ns4 + w];
    if (node_g >= 0) {
        float4 r        = part_s[0][w][lane];
        const float4 p1 = part_s[1][w][lane];
        const float4 p2 = part_s[2][w][lane];
        const float4 p3 = part_s[3][w][lane];
        const float4 bs = *(const float4*)(b + s * DIM + tile * 64 + g4);
        r.x = tanhf(r.x + p1.x + p2.x + p3.x + bs.x);
        r.y = tanhf(r.y + p1.y + p2.y + p3.y + bs.y);
        r.z = tanhf(r.z + p1.z + p2.z + p3.z + bs.z);
        r.w = tanhf(r.w + p1.w + p2.w + p3.w + bs.w);
        *(float4*)(enc + (size_t)node_g * DIM + tile * 64 + g4) = r;
    }
}

// ===== launch 3 (and fallback): grouped level reading enc (cached) =====
__global__ __launch_bounds__(256) void grouped_enc(const int* __restrict__ x_sym,
                                                   const float* __restrict__ W,
                                                   const float* __restrict__ b,
                                                   float* __restrict__ enc,
                                                   const int* __restrict__ order,
                                                   int level_off) {
    const int base = (blockIdx.x >> 2) * GRP + level_off;
    const int tile = blockIdx.x & 3;
    const int n0 = order[base];
    if (n0 < 0) return;
    const int s = x_sym[n0];
    const int t = threadIdx.x;
    const int w = t >> 6;
    const int lane = t & 63;
    __shared__ float  mean_s[GRP][MPAD];
    __shared__ float4 part_s[4][4][64];
    {
        const int c = lane << 2;
        #pragma unroll
        for (int j = 0; j < 4; ++j) {
            const int node = order[base + w * 4 + j];
            float4 m = make_float4(0.f, 0.f, 0.f, 0.f);
            if (node >= 0) {
                const int c0 = 2 * node + 1;
                const float4 ea = *(const float4*)(enc + (size_t)c0 * DIM + c);
                const float4 eb = *(const float4*)(enc + (size_t)(c0 + 1) * DIM + c);
                m.x = 0.5f * (ea.x + eb.x);
                m.y = 0.5f * (ea.y + eb.y);
                m.z = 0.5f * (ea.z + eb.z);
                m.w = 0.5f * (ea.w + eb.w);
            }
            *(float4*)(&mean_s[w * 4 + j][c]) = m;
        }
    }
    __syncthreads();
    const int ns4 = (lane >> 4) << 2;
    const int g4  = (lane & 15) << 2;
    gemm_core(W + ((size_t)s << 16) + (size_t)(w * 64) * DIM + tile * 64 + g4,
              mean_s, part_s, w, lane);
    __syncthreads();
    const int node_g = order[base + ns4 + w];
    if (node_g >= 0) {
        float4 r        = part_s[0][w][lane];
        const float4 p1 = part_s[1][w][lane];
        const float4 p2 = part_s[2][w][lane];
        const float4 p3 = part_s[3][w][lane];
        const float4 bs = *(const float4*)(b + s * DIM + tile * 64 + g4);
        r.x = tanhf(r.x + p1.x + p2.x + p3.x + bs.x);
        r.y = tanhf(r.y + p1.y + p2.y + p3.y + bs.y);
        r.z = tanhf(r.z + p1.z + p2.z + p3.z + bs.z);
        r.w = tanhf(r.w + p1.w + p2.w + p3.w + bs.w);
        *(float4*)(enc + (size_t)node_g * DIM + tile * 64 + g4) = r;
    }
}

// ===== launch 4: grouped level 9 + cnt-chained levels 8..0 + head =====
__global__ __launch_bounds__(256, 4) void tail_kernel(const int* __restrict__ x_sym,
                                                      const float* __restrict__ W,
                                                      const float* __restrict__ b,
                                                      float* __restrict__ enc,
                                                      const int* __restrict__ order,
                                                      int* __restrict__ cnt,
                                                      const float* __restrict__ W_out,
                                                      const float* __restrict__ b_out,
                                                      float* __restrict__ out) {
    __shared__ float  mean_s[GRP][MPAD];
    __shared__ float4 part_s[4][4][64];
    const int t = threadIdx.x;
    const int w = t >> 6;
    const int lane = t & 63;
    const int bid = blockIdx.x;

    // ---- phase 1: grouped level 9 (reads level-10 enc, cached; writes uncached) ----
    if (bid < G9_ITEMS) {
        const int base = (bid >> 2) * GRP + O9;
        const int tile = bid & 3;
        const int n0 = order[base];
        if (n0 >= 0) {
            const int s = x_sym[n0];
            const int c = lane << 2;
            #pragma unroll
            for (int j = 0; j < 4; ++j) {
                const int node = order[base + w * 4 + j];
                float4 m = make_float4(0.f, 0.f, 0.f, 0.f);
                if (node >= 0) {
                    const int c0 = 2 * node + 1;
                    const float4 ea = *(const float4*)(enc + (size_t)c0 * DIM + c);
                    const float4 eb = *(const float4*)(enc + (size_t)(c0 + 1) * DIM + c);
                    m.x = 0.5f * (ea.x + eb.x);
                    m.y = 0.5f * (ea.y + eb.y);
                    m.z = 0.5f * (ea.z + eb.z);
                    m.w = 0.5f * (ea.w + eb.w);
                }
                *(float4*)(&mean_s[w * 4 + j][c]) = m;
            }
            __syncthreads();
            const int ns4 = (lane >> 4) << 2;
            const int g4  = (lane & 15) << 2;
            gemm_core(W + ((size_t)s << 16) + (size_t)(w * 64) * DIM + tile * 64 + g4,
                      mean_s, part_s, w, lane);
            __syncthreads();
            const int node_g = order[base + ns4 + w];
            if (node_g >= 0) {
                float4 r        = part_s[0][w][lane];
                const float4 p1 = part_s[1][w][lane];
                const float4 p2 = part_s[2][w][lane];
                const float4 p3 = part_s[3][w][lane];
                const float4 bs = *(const float4*)(b + s * DIM + tile * 64 + g4);
                r.x = tanhf(r.x + p1.x + p2.x + p3.x + bs.x);
                r.y = tanhf(r.y + p1.y + p2.y + p3.y + bs.y);
                r.z = tanhf(r.z + p1.z + p2.z + p3.z + bs.z);
                r.w = tanhf(r.w + p1.w + p2.w + p3.w + bs.w);
                float* ep = enc + (size_t)node_g * DIM + tile * 64 + g4;
                st2(ep, r.x, r.y);
                st2(ep + 2, r.z, r.w);
            }
            __syncthreads();   // drain enc stores (vmcnt 0) before counting
            if (t < 16) {
                const int ng = order[base + t];
                if (ng >= 0) addi(&cnt[ng]);
            }
        }
        __syncthreads();
    }

    // ---- phase 2: levels 8..0, cnt-chained; W prefetched under the spin ----
    float* smean = (float*)&mean_s[0][0];
    float* spart = (float*)&part_s[0][0][0];
    for (int d = 8; d >= 0; --d) {
        const int items = 4 << d;
        if (bid >= items) return;   // retire forever
        const int node = (1 << d) - 1 + (bid >> 2);
        const int tile = bid & 3;
        const int c0 = 2 * node + 1;
        const int cc = tile * 64 + lane;
        const int s = x_sym[node];

        // prefetch this block's 64x64 W tile into registers (issued pre-spin;
        // the 64 KB L2 stream completes while we wait for the children)
        const float* Wp = W + ((size_t)s << 16) + (size_t)(w * 64) * DIM + cc;
        float wreg[64];
        #pragma unroll
        for (int i = 0; i < 64; ++i) wreg[i] = Wp[(size_t)i * DIM];

        if (t < 2) spin4(&cnt[c0 + t]);
        __syncthreads();

        if (t < 128) {   // stage mean: 8B uncached loads, 2 per thread
            const int o = t << 1;
            const float2 a = ld2(enc + (size_t)c0 * DIM + o);
            const float2 bb = ld2(enc + (size_t)(c0 + 1) * DIM + o);
            *(float2*)&smean[o] = make_float2(0.5f * (a.x + bb.x), 0.5f * (a.y + bb.y));
        }
        __syncthreads();

        float acc0 = 0.0f, acc1 = 0.0f;
        const float* sm = smean + w * 64;
        #pragma unroll
        for (int i = 0; i < 64; i += 2) {
            acc0 = fmaf(sm[i], wreg[i], acc0);
            acc1 = fmaf(sm[i + 1], wreg[i + 1], acc1);
        }
        spart[t] = acc0 + acc1;
        __syncthreads();
        if (t < 64) {
            float r = spart[t] + spart[t + 64] + spart[t + 128] + spart[t + 192];
            r += b[s * DIM + tile * 64 + t];
            st1f(enc + (size_t)node * DIM + tile * 64 + t, tanhf(r));
        }
        __syncthreads();   // drain stores before counting
        if (t == 0) addi(&cnt[node]);
        __syncthreads();   // LDS reuse guard
    }

    // ---- head: block 0 ----
    if (bid == 0) {
        if (t == 0) spin4(&cnt[0]);
        __syncthreads();
        const float e = ld1(enc + t);
        float p[10];
        #pragma unroll
        for (int o = 0; o < 10; ++o) p[o] = e * W_out[t * 10 + o];
        #pragma unroll
        for (int o = 0; o < 10; ++o)
            #pragma unroll
            for (int k = 32; k >= 1; k >>= 1) p[o] += __shfl_xor(p[o], k, 64);
        float* hp = (float*)&part_s[0][0][0];
        if (lane == 0) {
            #pragma unroll
            for (int o = 0; o < 10; ++o) hp[w * 10 + o] = p[o];
        }
        __syncthreads();
        if (t < 10) out[t] = b_out[t] + hp[t] + hp[10 + t] + hp[20 + t] + hp[30 + t];
    }
}

// ======================= generic / coop-fail fallbacks =======================
__global__ __launch_bounds__(256) void level_small(const int* __restrict__ x_sym,
                                                   const float* __restrict__ W,
                                                   const float* __restrict__ b,
                                                   float* __restrict__ enc,
                                                   int lo, int N) {
    const int node = lo + (blockIdx.x >> 2);
    const int tile = blockIdx.x & 3;
    const int t = threadIdx.x;
    const int lane = t & 63;
    const int c = tile * 64 + lane;
    __shared__ float mean_s[DIM];
    __shared__ float part[256];
    const int s = x_sym[node];
    const int c0 = 2 * node + 1;
    float m = 0.0f;
    if (c0 < N)
        m = 0.5f * (enc[(size_t)c0 * DIM + t] + enc[(size_t)(c0 + 1) * DIM + t]);
    mean_s[t] = m;
    __syncthreads();
    float acc = 0.0f;
    if (c0 < N) {
        const float* __restrict__ Ws = W + ((size_t)s << 16);
        const int d0 = (t >> 6) * 64;
        #pragma unroll 8
        for (int d = d0; d < d0 + 64; ++d)
            acc = fmaf(mean_s[d], Ws[d * DIM + c], acc);
    }
    part[t] = acc;
    __syncthreads();
    if (t < 64) {
        float r = part[t] + part[t + 64] + part[t + 128] + part[t + 192];
        r += b[s * DIM + c];
        enc[(size_t)node * DIM + c] = tanhf(r);
    }
}

__global__ __launch_bounds__(256) void level_big(const int* __restrict__ x_sym,
                                                 const float* __restrict__ W,
                                                 const float* __restrict__ b,
                                                 float* __restrict__ enc,
                                                 int lo, int N) {
    const int node = lo + blockIdx.x;
    const int e = threadIdx.x;
    __shared__ float mean_s[DIM];
    const int s = x_sym[node];
    const int c0 = 2 * node + 1;
    float acc = b[s * DIM + e];
    if (c0 < N) {
        mean_s[e] = 0.5f * (enc[(size_t)c0 * DIM + e] + enc[(size_t)(c0 + 1) * DIM + e]);
        __syncthreads();
        const float* __restrict__ Ws = W + ((size_t)s << 16);
        #pragma unroll 8
        for (int d = 0; d < DIM; ++d)
            acc = fmaf(mean_s[d], Ws[d * DIM + e], acc);
    }
    enc[(size_t)node * DIM + e] = tanhf(acc);
}

__global__ __launch_bounds__(256) void out_kernel10(const float* __restrict__ enc,
                                                    const float* __restrict__ W_out,
                                                    const float* __restrict__ b_out,
                                                    float* __restrict__ out) {
    const int t = threadIdx.x;
    const float e = enc[t];
    float p[10];
    #pragma unroll
    for (int o = 0; o < 10; ++o) p[o] = e * W_out[t * 10 + o];
    #pragma unroll
    for (int o = 0; o < 10; ++o)
        #pragma unroll
        for (int k = 32; k >= 1; k >>= 1) p[o] += __shfl_xor(p[o], k, 64);
    __shared__ float part[4][10];
    if ((t & 63) == 0) {
        #pragma unroll
        for (int o = 0; o < 10; ++o) part[t >> 6][o] = p[o];
    }
    __syncthreads();
    if (t < 10) out[t] = b_out[t] + part[0][t] + part[1][t] + part[2][t] + part[3][t];
}

__global__ void out_kernel(const float* __restrict__ enc,
                           const float* __restrict__ W_out,
                           const float* __restrict__ b_out,
                           float* __restrict__ out, int outn) {
    const int o = threadIdx.x;
    if (o < outn) {
        float acc = b_out[o];
        for (int d = 0; d < DIM; ++d)
            acc = fmaf(enc[d], W_out[d * outn + o], acc);
        out[o] = acc;
    }
}

extern "C" void kernel_launch(void* const* d_in, const int* in_sizes, int n_in,
                              void* d_out, int out_size, void* d_ws, size_t ws_size,
                              hipStream_t stream) {
    const int*   x_sym = (const int*)d_in[0];
    const float* W     = (const float*)d_in[2];
    const float* b     = (const float*)d_in[3];
    const float* W_out = (const float*)d_in[4];
    const float* b_out = (const float*)d_in[5];
    float* out = (float*)d_out;
    float* enc = (float*)d_ws;                      // N x 256 fp32
    const int N = in_sizes[0];

    int depth = 0;
    while (((1 << depth) - 1) < N) ++depth;

    const size_t need = (size_t)16383 * DIM * 4 + (OTOT + 1024) * 4;
    if (N == (1 << 14) - 1 && out_size == 10 && ws_size >= need) {
        float* T   = enc + (size_t)8191 * DIM;       // combo table in unused leaf rows
        int* order = (int*)(enc + (size_t)N * DIM);  // OTOT ints
        int* cnt   = order + OTOT;                   // 1024 ints

        combo_sort_zero<<<580, 256, 0, stream>>>(x_sym, W, b, T, order, cnt);
        grouped_T<<<G11_BLOCKS, 256, 0, stream>>>(x_sym, W, b, enc, T, order);
        grouped_enc<<<G10_BLOCKS, 256, 0, stream>>>(x_sym, W, b, enc, order, O10);

        void* args[] = { (void*)&x_sym, (void*)&W, (void*)&b, (void*)&enc,
                         (void*)&order, (void*)&cnt,
                         (void*)&W_out, (void*)&b_out, (void*)&out };
        hipError_t err = hipLaunchCooperativeKernel((const void*)tail_kernel,
                                                    dim3(NBLK), dim3(256),
                                                    args, 0, stream);
        if (err == hipSuccess) return;
        (void)hipGetLastError();
        // coop failed: finish with proven multi-launch (level 9 .. head)
        grouped_enc<<<G9_ITEMS, 256, 0, stream>>>(x_sym, W, b, enc, order, O9);
        for (int d = 8; d >= 0; --d)
            level_small<<<(1 << d) * 4, 256, 0, stream>>>(x_sym, W, b, enc,
                                                          (1 << d) - 1, N);
        out_kernel10<<<1, 256, 0, stream>>>(enc, W_out, b_out, out);
    } else {
        for (int d = depth - 1; d >= 0; --d) {
            int lo = (1 << d) - 1;
            int n = (1 << d);
            if (lo + n > N) n = N - lo;
            if (n >= 256)
                level_big<<<n, 256, 0, stream>>>(x_sym, W, b, enc, lo, N);
            else
                level_small<<<n * 4, 256, 0, stream>>>(x_sym, W, b, enc, lo, N);
        }
        out_kernel<<<1, 64, 0, stream>>>(enc, W_out, b_out, out, out_size);
    }
}

// Round 9
// 90.978 us; speedup vs baseline: 17.6456x; 1.2914x over previous
//
#include <hip/hip_runtime.h>

#define DIM 256
#define GRP 16
#define MPAD 260
#define NBLK 1024

// order[] layout (ints): level 11 @ 0 (cap 2288), level 10 @ 2288 (cap 1264),
// level 9 @ 3552 (cap 752). cnt (1024 ints) follows.
#define O11 0
#define O10 2288
#define O9  3552
#define OTOT 4352
#define G11_BLOCKS 572
#define G10_BLOCKS 316
#define G9_ITEMS   188

#define FMA4(a, sc, v) \
    a.x = fmaf((sc), (v).x, a.x); a.y = fmaf((sc), (v).y, a.y); \
    a.z = fmaf((sc), (v).z, a.z); a.w = fmaf((sc), (v).w, a.w);

// ---- agent-scope (LLC-coherent) ops: flags + small tail rows only ----
__device__ __forceinline__ float ld1(const float* p) {
    union { unsigned int u; float f; } cv;
    cv.u = __hip_atomic_load((const unsigned int*)p, __ATOMIC_RELAXED,
                             __HIP_MEMORY_SCOPE_AGENT);
    return cv.f;
}
__device__ __forceinline__ float2 ld2(const float* p) {
    union { unsigned long long u; float2 f; } cv;
    cv.u = __hip_atomic_load((const unsigned long long*)p, __ATOMIC_RELAXED,
                             __HIP_MEMORY_SCOPE_AGENT);
    return cv.f;
}
__device__ __forceinline__ void st1f(float* p, float x) {
    union { unsigned int u; float f; } cv; cv.f = x;
    __hip_atomic_store((unsigned int*)p, cv.u, __ATOMIC_RELAXED,
                       __HIP_MEMORY_SCOPE_AGENT);
}
__device__ __forceinline__ void st2(float* p, float x, float y) {
    union { unsigned long long u; float2 f; } cv;
    cv.f = make_float2(x, y);
    __hip_atomic_store((unsigned long long*)p, cv.u, __ATOMIC_RELAXED,
                       __HIP_MEMORY_SCOPE_AGENT);
}
__device__ __forceinline__ int addi(int* p) {
    return __hip_atomic_fetch_add(p, 1, __ATOMIC_RELAXED, __HIP_MEMORY_SCOPE_AGENT);
}
__device__ __forceinline__ void spin4(const int* f) {
    if (__hip_atomic_load(f, __ATOMIC_RELAXED, __HIP_MEMORY_SCOPE_AGENT) >= 4) return;
    int guard = 0;
    do {
        __builtin_amdgcn_s_sleep(1);
        if (++guard > (1 << 20)) break;   // never hard-hang the harness
    } while (__hip_atomic_load(f, __ATOMIC_RELAXED, __HIP_MEMORY_SCOPE_AGENT) < 4);
}

// shared 16-node x 64-col FMA core. Ws pre-offset by s, K-chunk, tile, g4.
__device__ __forceinline__ void gemm_core(const float* __restrict__ Ws,
                                          const float mean_s[GRP][MPAD],
                                          float4 part_s[4][4][64],
                                          int w, int lane) {
    const int ns4 = (lane >> 4) << 2;
    float4 acc0 = make_float4(0, 0, 0, 0), acc1 = acc0, acc2 = acc0, acc3 = acc0;
    const int dbase = w * 64;
    #pragma unroll 4
    for (int dd = 0; dd < 64; dd += 4) {
        const float4 w0 = *(const float4*)(Ws + (size_t)(dd + 0) * DIM);
        const float4 w1 = *(const float4*)(Ws + (size_t)(dd + 1) * DIM);
        const float4 w2 = *(const float4*)(Ws + (size_t)(dd + 2) * DIM);
        const float4 w3 = *(const float4*)(Ws + (size_t)(dd + 3) * DIM);
        const int dk = dbase + dd;
        const float4 m0 = *(const float4*)(&mean_s[ns4 + 0][dk]);
        const float4 m1 = *(const float4*)(&mean_s[ns4 + 1][dk]);
        const float4 m2 = *(const float4*)(&mean_s[ns4 + 2][dk]);
        const float4 m3 = *(const float4*)(&mean_s[ns4 + 3][dk]);
        FMA4(acc0, m0.x, w0); FMA4(acc0, m0.y, w1); FMA4(acc0, m0.z, w2); FMA4(acc0, m0.w, w3);
        FMA4(acc1, m1.x, w0); FMA4(acc1, m1.y, w1); FMA4(acc1, m1.z, w2); FMA4(acc1, m1.w, w3);
        FMA4(acc2, m2.x, w0); FMA4(acc2, m2.y, w1); FMA4(acc2, m2.z, w2); FMA4(acc2, m2.w, w3);
        FMA4(acc3, m3.x, w0); FMA4(acc3, m3.y, w1); FMA4(acc3, m3.z, w2); FMA4(acc3, m3.w, w3);
    }
    part_s[w][0][lane] = acc0;
    part_s[w][1][lane] = acc1;
    part_s[w][2][lane] = acc2;
    part_s[w][3][lane] = acc3;
}

__device__ __forceinline__ void unpair(int p, int& pa, int& pb) {
    int a = 0, rem = p;
    while (rem >= 16 - a) { rem -= 16 - a; ++a; }
    pa = a; pb = a + rem;
}

// ===== launch 1: combo table (level 12 memoized) + 3 parallel sorts + cnt zero =====
__global__ __launch_bounds__(256) void combo_sort_zero(const int* __restrict__ x_sym,
                                                       const float* __restrict__ W,
                                                       const float* __restrict__ b,
                                                       float* __restrict__ T,
                                                       int* __restrict__ order,
                                                       int* __restrict__ cnt) {
    __shared__ float  mean_s[GRP][MPAD];
    __shared__ float4 part_s[4][4][64];
    __shared__ int cnt_s[16], cur_s[16];
    const int t = threadIdx.x;
    const int w = t >> 6;
    const int lane = t & 63;
    const int bid = blockIdx.x;

    if (bid < 576) {  // ---- combo: T[s][pa][pb] for all pa<=pb, symmetric fill ----
        const int s = bid / 36;
        const int rem = bid % 36;
        const int chunk = rem >> 2;
        const int tile = rem & 3;
        {
            const int c = lane << 2;
            #pragma unroll
            for (int j = 0; j < 4; ++j) {
                const int p = chunk * 16 + w * 4 + j;
                float4 m = make_float4(0.f, 0.f, 0.f, 0.f);
                if (p < 136) {
                    int pa, pb; unpair(p, pa, pb);
                    const float4 ba = *(const float4*)(b + pa * DIM + c);
                    const float4 bb = *(const float4*)(b + pb * DIM + c);
                    m.x = 0.5f * (tanhf(ba.x) + tanhf(bb.x));
                    m.y = 0.5f * (tanhf(ba.y) + tanhf(bb.y));
                    m.z = 0.5f * (tanhf(ba.z) + tanhf(bb.z));
                    m.w = 0.5f * (tanhf(ba.w) + tanhf(bb.w));
                }
                *(float4*)(&mean_s[w * 4 + j][c]) = m;
            }
        }
        __syncthreads();
        const int ns4 = (lane >> 4) << 2;
        const int g4  = (lane & 15) << 2;
        gemm_core(W + ((size_t)s << 16) + (size_t)(w * 64) * DIM + tile * 64 + g4,
                  mean_s, part_s, w, lane);
        __syncthreads();
        const int p = chunk * 16 + ns4 + w;
        if (p < 136) {
            int pa, pb; unpair(p, pa, pb);
            float4 r        = part_s[0][w][lane];
            const float4 p1 = part_s[1][w][lane];
            const float4 p2 = part_s[2][w][lane];
            const float4 p3 = part_s[3][w][lane];
            const float4 bs = *(const float4*)(b + s * DIM + tile * 64 + g4);
            r.x = tanhf(r.x + p1.x + p2.x + p3.x + bs.x);
            r.y = tanhf(r.y + p1.y + p2.y + p3.y + bs.y);
            r.z = tanhf(r.z + p1.z + p2.z + p3.z + bs.z);
            r.w = tanhf(r.w + p1.w + p2.w + p3.w + bs.w);
            *(float4*)(T + (size_t)((s * 16 + pa) * 16 + pb) * DIM + tile * 64 + g4) = r;
            if (pa != pb)
                *(float4*)(T + (size_t)((s * 16 + pb) * 16 + pa) * DIM + tile * 64 + g4) = r;
        }
    } else if (bid <= 578) {  // ---- 3 parallel sorts: levels 11, 10, 9 ----
        const int li = bid - 576;
        const int d = 11 - li;
        const int off = (li == 0) ? O11 : (li == 1) ? O10 : O9;
        const int lo = (1 << d) - 1;
        const int n = 1 << d;
        for (int i = t; i < n + 240; i += 256) order[off + i] = -1;
        if (t < 16) cnt_s[t] = 0;
        __syncthreads();
        for (int i = t; i < n; i += 256) atomicAdd(&cnt_s[x_sym[lo + i]], 1);
        __syncthreads();
        if (t == 0) {
            int run = off;
            for (int s2 = 0; s2 < 16; ++s2) {
                cur_s[s2] = run;
                run += ((cnt_s[s2] + GRP - 1) / GRP) * GRP;
            }
        }
        __syncthreads();
        for (int i = t; i < n; i += 256) {
            const int pos = atomicAdd(&cur_s[x_sym[lo + i]], 1);
            order[pos] = lo + i;
        }
    } else {  // ---- bid 579: zero cnt (1024 ints); visible at LLC after launch ends ----
        for (int i = t; i < 1024; i += 256) cnt[i] = 0;
    }
}

// ===== launch 2: level 11, staging via combo table lookup =====
__global__ __launch_bounds__(256) void grouped_T(const int* __restrict__ x_sym,
                                                 const float* __restrict__ W,
                                                 const float* __restrict__ b,
                                                 float* __restrict__ enc,
                                                 const float* __restrict__ T,
                                                 const int* __restrict__ order) {
    const int base = (blockIdx.x >> 2) * GRP + O11;
    const int tile = blockIdx.x & 3;
    const int n0 = order[base];
    if (n0 < 0) return;
    const int s = x_sym[n0];
    const int t = threadIdx.x;
    const int w = t >> 6;
    const int lane = t & 63;
    __shared__ float  mean_s[GRP][MPAD];
    __shared__ float4 part_s[4][4][64];
    {
        const int c = lane << 2;
        #pragma unroll
        for (int j = 0; j < 4; ++j) {
            const int node = order[base + w * 4 + j];
            float4 m = make_float4(0.f, 0.f, 0.f, 0.f);
            if (node >= 0) {
                const int c0 = 2 * node + 1, c1 = c0 + 1;
                const float* r0 = T + (size_t)((x_sym[c0] * 16 + x_sym[2 * c0 + 1]) * 16
                                               + x_sym[2 * c0 + 2]) * DIM;
                const float* r1 = T + (size_t)((x_sym[c1] * 16 + x_sym[2 * c1 + 1]) * 16
                                               + x_sym[2 * c1 + 2]) * DIM;
                const float4 ea = *(const float4*)(r0 + c);
                const float4 eb = *(const float4*)(r1 + c);
                m.x = 0.5f * (ea.x + eb.x);
                m.y = 0.5f * (ea.y + eb.y);
                m.z = 0.5f * (ea.z + eb.z);
                m.w = 0.5f * (ea.w + eb.w);
            }
            *(float4*)(&mean_s[w * 4 + j][c]) = m;
        }
    }
    __syncthreads();
    const int ns4 = (lane >> 4) << 2;
    const int g4  = (lane & 15) << 2;
    gemm_core(W + ((size_t)s << 16) + (size_t)(w * 64) * DIM + tile * 64 + g4,
              mean_s, part_s, w, lane);
    __syncthreads();
    const int node_g = order[base + ns4 + w];
    if (node_g >= 0) {
        float4 r        = part_s[0][w][lane];
        const float4 p1 = part_s[1][w][lane];
        const float4 p2 = part_s[2][w][lane];
        const float4 p3 = part_s[3][w][lane];
        const float4 bs = *(const float4*)(b + s * DIM + tile * 64 + g4);
        r.x = tanhf(r.x + p1.x + p2.x + p3.x + bs.x);
        r.y = tanhf(r.y + p1.y + p2.y + p3.y + bs.y);
        r.z = tanhf(r.z + p1.z + p2.z + p3.z + bs.z);
        r.w = tanhf(r.w + p1.w + p2.w + p3.w + bs.w);
        *(float4*)(enc + (size_t)node_g * DIM + tile * 64 + g4) = r;
    }
}

// ===== launch 3 (and fallback): grouped level reading enc (cached) =====
__global__ __launch_bounds__(256) void grouped_enc(const int* __restrict__ x_sym,
                                                   const float* __restrict__ W,
                                                   const float* __restrict__ b,
                                                   float* __restrict__ enc,
                                                   const int* __restrict__ order,
                                                   int level_off) {
    const int base = (blockIdx.x >> 2) * GRP + level_off;
    const int tile = blockIdx.x & 3;
    const int n0 = order[base];
    if (n0 < 0) return;
    const int s = x_sym[n0];
    const int t = threadIdx.x;
    const int w = t >> 6;
    const int lane = t & 63;
    __shared__ float  mean_s[GRP][MPAD];
    __shared__ float4 part_s[4][4][64];
    {
        const int c = lane << 2;
        #pragma unroll
        for (int j = 0; j < 4; ++j) {
            const int node = order[base + w * 4 + j];
            float4 m = make_float4(0.f, 0.f, 0.f, 0.f);
            if (node >= 0) {
                const int c0 = 2 * node + 1;
                const float4 ea = *(const float4*)(enc + (size_t)c0 * DIM + c);
                const float4 eb = *(const float4*)(enc + (size_t)(c0 + 1) * DIM + c);
                m.x = 0.5f * (ea.x + eb.x);
                m.y = 0.5f * (ea.y + eb.y);
                m.z = 0.5f * (ea.z + eb.z);
                m.w = 0.5f * (ea.w + eb.w);
            }
            *(float4*)(&mean_s[w * 4 + j][c]) = m;
        }
    }
    __syncthreads();
    const int ns4 = (lane >> 4) << 2;
    const int g4  = (lane & 15) << 2;
    gemm_core(W + ((size_t)s << 16) + (size_t)(w * 64) * DIM + tile * 64 + g4,
              mean_s, part_s, w, lane);
    __syncthreads();
    const int node_g = order[base + ns4 + w];
    if (node_g >= 0) {
        float4 r        = part_s[0][w][lane];
        const float4 p1 = part_s[1][w][lane];
        const float4 p2 = part_s[2][w][lane];
        const float4 p3 = part_s[3][w][lane];
        const float4 bs = *(const float4*)(b + s * DIM + tile * 64 + g4);
        r.x = tanhf(r.x + p1.x + p2.x + p3.x + bs.x);
        r.y = tanhf(r.y + p1.y + p2.y + p3.y + bs.y);
        r.z = tanhf(r.z + p1.z + p2.z + p3.z + bs.z);
        r.w = tanhf(r.w + p1.w + p2.w + p3.w + bs.w);
        *(float4*)(enc + (size_t)node_g * DIM + tile * 64 + g4) = r;
    }
}

// ===== launch 4 (PLAIN launch, exact-fit co-resident): level 9 + chained 8..0 + head =====
__global__ __launch_bounds__(256, 4) void tail_kernel(const int* __restrict__ x_sym,
                                                      const float* __restrict__ W,
                                                      const float* __restrict__ b,
                                                      float* __restrict__ enc,
                                                      const int* __restrict__ order,
                                                      int* __restrict__ cnt,
                                                      const float* __restrict__ W_out,
                                                      const float* __restrict__ b_out,
                                                      float* __restrict__ out) {
    __shared__ float  mean_s[GRP][MPAD];
    __shared__ float4 part_s[4][4][64];
    const int t = threadIdx.x;
    const int w = t >> 6;
    const int lane = t & 63;
    const int bid = blockIdx.x;

    // ---- phase 1: grouped level 9 (reads level-10 enc, cached; writes uncached) ----
    if (bid < G9_ITEMS) {
        const int base = (bid >> 2) * GRP + O9;
        const int tile = bid & 3;
        const int n0 = order[base];
        if (n0 >= 0) {
            const int s = x_sym[n0];
            const int c = lane << 2;
            #pragma unroll
            for (int j = 0; j < 4; ++j) {
                const int node = order[base + w * 4 + j];
                float4 m = make_float4(0.f, 0.f, 0.f, 0.f);
                if (node >= 0) {
                    const int c0 = 2 * node + 1;
                    const float4 ea = *(const float4*)(enc + (size_t)c0 * DIM + c);
                    const float4 eb = *(const float4*)(enc + (size_t)(c0 + 1) * DIM + c);
                    m.x = 0.5f * (ea.x + eb.x);
                    m.y = 0.5f * (ea.y + eb.y);
                    m.z = 0.5f * (ea.z + eb.z);
                    m.w = 0.5f * (ea.w + eb.w);
                }
                *(float4*)(&mean_s[w * 4 + j][c]) = m;
            }
            __syncthreads();
            const int ns4 = (lane >> 4) << 2;
            const int g4  = (lane & 15) << 2;
            gemm_core(W + ((size_t)s << 16) + (size_t)(w * 64) * DIM + tile * 64 + g4,
                      mean_s, part_s, w, lane);
            __syncthreads();
            const int node_g = order[base + ns4 + w];
            if (node_g >= 0) {
                float4 r        = part_s[0][w][lane];
                const float4 p1 = part_s[1][w][lane];
                const float4 p2 = part_s[2][w][lane];
                const float4 p3 = part_s[3][w][lane];
                const float4 bs = *(const float4*)(b + s * DIM + tile * 64 + g4);
                r.x = tanhf(r.x + p1.x + p2.x + p3.x + bs.x);
                r.y = tanhf(r.y + p1.y + p2.y + p3.y + bs.y);
                r.z = tanhf(r.z + p1.z + p2.z + p3.z + bs.z);
                r.w = tanhf(r.w + p1.w + p2.w + p3.w + bs.w);
                float* ep = enc + (size_t)node_g * DIM + tile * 64 + g4;
                st2(ep, r.x, r.y);
                st2(ep + 2, r.z, r.w);
            }
            __syncthreads();   // drain enc stores (vmcnt 0) before counting
            if (t < 16) {
                const int ng = order[base + t];
                if (ng >= 0) addi(&cnt[ng]);
            }
        }
        __syncthreads();
    }

    // ---- phase 2: levels 8..0, cnt-chained; W PINNED-prefetched under the spin ----
    float* smean = (float*)&mean_s[0][0];
    float* spart = (float*)&part_s[0][0][0];
    for (int d = 8; d >= 0; --d) {
        const int items = 4 << d;
        if (bid >= items) return;   // retire forever
        const int node = (1 << d) - 1 + (bid >> 2);
        const int tile = bid & 3;
        const int c0 = 2 * node + 1;
        const int cc = tile * 64 + lane;
        const int s = x_sym[node];

        // prefetch this block's 256x64 W tile into registers BEFORE the spin;
        // asm pin forces materialization here (defeats load sinking past the
        // spin — round-8 showed VGPR=52 i.e. the plain version was sunk).
        const float* Wp = W + ((size_t)s << 16) + (size_t)(w * 64) * DIM + cc;
        float wreg[64];
        #pragma unroll
        for (int i = 0; i < 64; ++i) wreg[i] = Wp[(size_t)i * DIM];
        #pragma unroll
        for (int i = 0; i < 64; ++i) asm volatile("" : "+v"(wreg[i]));

        if (t < 2) spin4(&cnt[c0 + t]);
        __syncthreads();

        if (t < 128) {   // stage mean: 8B uncached loads, 2 per thread
            const int o = t << 1;
            const float2 a = ld2(enc + (size_t)c0 * DIM + o);
            const float2 bb = ld2(enc + (size_t)(c0 + 1) * DIM + o);
            *(float2*)&smean[o] = make_float2(0.5f * (a.x + bb.x), 0.5f * (a.y + bb.y));
        }
        __syncthreads();

        float acc0 = 0.0f, acc1 = 0.0f;
        const float* sm = smean + w * 64;
        #pragma unroll
        for (int i = 0; i < 64; i += 2) {
            acc0 = fmaf(sm[i], wreg[i], acc0);
            acc1 = fmaf(sm[i + 1], wreg[i + 1], acc1);
        }
        spart[t] = acc0 + acc1;
        __syncthreads();
        if (t < 64) {
            float r = spart[t] + spart[t + 64] + spart[t + 128] + spart[t + 192];
            r += b[s * DIM + tile * 64 + t];
            st1f(enc + (size_t)node * DIM + tile * 64 + t, tanhf(r));
        }
        __syncthreads();   // drain stores before counting
        if (t == 0) addi(&cnt[node]);
        __syncthreads();   // LDS reuse guard
    }

    // ---- head: block 0 ----
    if (bid == 0) {
        if (t == 0) spin4(&cnt[0]);
        __syncthreads();
        const float e = ld1(enc + t);
        float p[10];
        #pragma unroll
        for (int o = 0; o < 10; ++o) p[o] = e * W_out[t * 10 + o];
        #pragma unroll
        for (int o = 0; o < 10; ++o)
            #pragma unroll
            for (int k = 32; k >= 1; k >>= 1) p[o] += __shfl_xor(p[o], k, 64);
        float* hp = (float*)&part_s[0][0][0];
        if (lane == 0) {
            #pragma unroll
            for (int o = 0; o < 10; ++o) hp[w * 10 + o] = p[o];
        }
        __syncthreads();
        if (t < 10) out[t] = b_out[t] + hp[t] + hp[10 + t] + hp[20 + t] + hp[30 + t];
    }
}

// ======================= generic-shape fallbacks =======================
__global__ __launch_bounds__(256) void level_small(const int* __restrict__ x_sym,
                                                   const float* __restrict__ W,
                                                   const float* __restrict__ b,
                                                   float* __restrict__ enc,
                                                   int lo, int N) {
    const int node = lo + (blockIdx.x >> 2);
    const int tile = blockIdx.x & 3;
    const int t = threadIdx.x;
    const int lane = t & 63;
    const int c = tile * 64 + lane;
    __shared__ float mean_s[DIM];
    __shared__ float part[256];
    const int s = x_sym[node];
    const int c0 = 2 * node + 1;
    float m = 0.0f;
    if (c0 < N)
        m = 0.5f * (enc[(size_t)c0 * DIM + t] + enc[(size_t)(c0 + 1) * DIM + t]);
    mean_s[t] = m;
    __syncthreads();
    float acc = 0.0f;
    if (c0 < N) {
        const float* __restrict__ Ws = W + ((size_t)s << 16);
        const int d0 = (t >> 6) * 64;
        #pragma unroll 8
        for (int d = d0; d < d0 + 64; ++d)
            acc = fmaf(mean_s[d], Ws[d * DIM + c], acc);
    }
    part[t] = acc;
    __syncthreads();
    if (t < 64) {
        float r = part[t] + part[t + 64] + part[t + 128] + part[t + 192];
        r += b[s * DIM + c];
        enc[(size_t)node * DIM + c] = tanhf(r);
    }
}

__global__ __launch_bounds__(256) void level_big(const int* __restrict__ x_sym,
                                                 const float* __restrict__ W,
                                                 const float* __restrict__ b,
                                                 float* __restrict__ enc,
                                                 int lo, int N) {
    const int node = lo + blockIdx.x;
    const int e = threadIdx.x;
    __shared__ float mean_s[DIM];
    const int s = x_sym[node];
    const int c0 = 2 * node + 1;
    float acc = b[s * DIM + e];
    if (c0 < N) {
        mean_s[e] = 0.5f * (enc[(size_t)c0 * DIM + e] + enc[(size_t)(c0 + 1) * DIM + e]);
        __syncthreads();
        const float* __restrict__ Ws = W + ((size_t)s << 16);
        #pragma unroll 8
        for (int d = 0; d < DIM; ++d)
            acc = fmaf(mean_s[d], Ws[d * DIM + e], acc);
    }
    enc[(size_t)node * DIM + e] = tanhf(acc);
}

__global__ void out_kernel(const float* __restrict__ enc,
                           const float* __restrict__ W_out,
                           const float* __restrict__ b_out,
                           float* __restrict__ out, int outn) {
    const int o = threadIdx.x;
    if (o < outn) {
        float acc = b_out[o];
        for (int d = 0; d < DIM; ++d)
            acc = fmaf(enc[d], W_out[d * outn + o], acc);
        out[o] = acc;
    }
}

extern "C" void kernel_launch(void* const* d_in, const int* in_sizes, int n_in,
                              void* d_out, int out_size, void* d_ws, size_t ws_size,
                              hipStream_t stream) {
    const int*   x_sym = (const int*)d_in[0];
    const float* W     = (const float*)d_in[2];
    const float* b     = (const float*)d_in[3];
    const float* W_out = (const float*)d_in[4];
    const float* b_out = (const float*)d_in[5];
    float* out = (float*)d_out;
    float* enc = (float*)d_ws;                      // N x 256 fp32
    const int N = in_sizes[0];

    int depth = 0;
    while (((1 << depth) - 1) < N) ++depth;

    const size_t need = (size_t)16383 * DIM * 4 + (OTOT + 1024) * 4;
    if (N == (1 << 14) - 1 && out_size == 10 && ws_size >= need) {
        float* T   = enc + (size_t)8191 * DIM;       // combo table in unused leaf rows
        int* order = (int*)(enc + (size_t)N * DIM);  // OTOT ints
        int* cnt   = order + OTOT;                   // 1024 ints

        combo_sort_zero<<<580, 256, 0, stream>>>(x_sym, W, b, T, order, cnt);
        grouped_T<<<G11_BLOCKS, 256, 0, stream>>>(x_sym, W, b, enc, T, order);
        grouped_enc<<<G10_BLOCKS, 256, 0, stream>>>(x_sym, W, b, enc, order, O10);
        // plain launch: 1024 blocks x 33KB LDS = exact-fit co-residency (4/CU x 256 CU)
        tail_kernel<<<NBLK, 256, 0, stream>>>(x_sym, W, b, enc, order, cnt,
                                              W_out, b_out, out);
    } else {
        for (int d = depth - 1; d >= 0; --d) {
            int lo = (1 << d) - 1;
            int n = (1 << d);
            if (lo + n > N) n = N - lo;
            if (n >= 256)
                level_big<<<n, 256, 0, stream>>>(x_sym, W, b, enc, lo, N);
            else
                level_small<<<n * 4, 256, 0, stream>>>(x_sym, W, b, enc, lo, N);
        }
        out_kernel<<<1, 64, 0, stream>>>(enc, W_out, b_out, out, out_size);
    }
}

// Round 10
// 66.840 us; speedup vs baseline: 24.0180x; 1.3611x over previous
//
#include <hip/hip_runtime.h>

#define DIM 256
#define GRP 16
#define MPAD 260
#define NBLK 1024
#define CSTR 32   // cnt stride in ints: one 128-B cacheline per node (anti-contention)

// order[] layout (ints): level 11 @ 0 (cap 2288), level 10 @ 2288 (cap 1264),
// level 9 @ 3552 (cap 752). cnt (1024*CSTR ints, line-padded) follows.
#define O11 0
#define O10 2288
#define O9  3552
#define OTOT 4352
#define G11_BLOCKS 572
#define G10_BLOCKS 316
#define G9_ITEMS   188

#define FMA4(a, sc, v) \
    a.x = fmaf((sc), (v).x, a.x); a.y = fmaf((sc), (v).y, a.y); \
    a.z = fmaf((sc), (v).z, a.z); a.w = fmaf((sc), (v).w, a.w);

// ---- agent-scope (LLC-coherent) ops: flags + small tail rows only ----
__device__ __forceinline__ float ld1(const float* p) {
    union { unsigned int u; float f; } cv;
    cv.u = __hip_atomic_load((const unsigned int*)p, __ATOMIC_RELAXED,
                             __HIP_MEMORY_SCOPE_AGENT);
    return cv.f;
}
__device__ __forceinline__ float2 ld2(const float* p) {
    union { unsigned long long u; float2 f; } cv;
    cv.u = __hip_atomic_load((const unsigned long long*)p, __ATOMIC_RELAXED,
                             __HIP_MEMORY_SCOPE_AGENT);
    return cv.f;
}
__device__ __forceinline__ void st1f(float* p, float x) {
    union { unsigned int u; float f; } cv; cv.f = x;
    __hip_atomic_store((unsigned int*)p, cv.u, __ATOMIC_RELAXED,
                       __HIP_MEMORY_SCOPE_AGENT);
}
__device__ __forceinline__ void st2(float* p, float x, float y) {
    union { unsigned long long u; float2 f; } cv;
    cv.f = make_float2(x, y);
    __hip_atomic_store((unsigned long long*)p, cv.u, __ATOMIC_RELAXED,
                       __HIP_MEMORY_SCOPE_AGENT);
}
__device__ __forceinline__ int addi(int* p) {
    return __hip_atomic_fetch_add(p, 1, __ATOMIC_RELAXED, __HIP_MEMORY_SCOPE_AGENT);
}
__device__ __forceinline__ void spin4(const int* f) {
    if (__hip_atomic_load(f, __ATOMIC_RELAXED, __HIP_MEMORY_SCOPE_AGENT) >= 4) return;
    int guard = 0;
    do {
        __builtin_amdgcn_s_sleep(1);
        if (++guard > (1 << 20)) break;   // never hard-hang the harness
    } while (__hip_atomic_load(f, __ATOMIC_RELAXED, __HIP_MEMORY_SCOPE_AGENT) < 4);
}

// shared 16-node x 64-col FMA core. Ws pre-offset by s, K-chunk, tile, g4.
__device__ __forceinline__ void gemm_core(const float* __restrict__ Ws,
                                          const float mean_s[GRP][MPAD],
                                          float4 part_s[4][4][64],
                                          int w, int lane) {
    const int ns4 = (lane >> 4) << 2;
    float4 acc0 = make_float4(0, 0, 0, 0), acc1 = acc0, acc2 = acc0, acc3 = acc0;
    const int dbase = w * 64;
    #pragma unroll 4
    for (int dd = 0; dd < 64; dd += 4) {
        const float4 w0 = *(const float4*)(Ws + (size_t)(dd + 0) * DIM);
        const float4 w1 = *(const float4*)(Ws + (size_t)(dd + 1) * DIM);
        const float4 w2 = *(const float4*)(Ws + (size_t)(dd + 2) * DIM);
        const float4 w3 = *(const float4*)(Ws + (size_t)(dd + 3) * DIM);
        const int dk = dbase + dd;
        const float4 m0 = *(const float4*)(&mean_s[ns4 + 0][dk]);
        const float4 m1 = *(const float4*)(&mean_s[ns4 + 1][dk]);
        const float4 m2 = *(const float4*)(&mean_s[ns4 + 2][dk]);
        const float4 m3 = *(const float4*)(&mean_s[ns4 + 3][dk]);
        FMA4(acc0, m0.x, w0); FMA4(acc0, m0.y, w1); FMA4(acc0, m0.z, w2); FMA4(acc0, m0.w, w3);
        FMA4(acc1, m1.x, w0); FMA4(acc1, m1.y, w1); FMA4(acc1, m1.z, w2); FMA4(acc1, m1.w, w3);
        FMA4(acc2, m2.x, w0); FMA4(acc2, m2.y, w1); FMA4(acc2, m2.z, w2); FMA4(acc2, m2.w, w3);
        FMA4(acc3, m3.x, w0); FMA4(acc3, m3.y, w1); FMA4(acc3, m3.z, w2); FMA4(acc3, m3.w, w3);
    }
    part_s[w][0][lane] = acc0;
    part_s[w][1][lane] = acc1;
    part_s[w][2][lane] = acc2;
    part_s[w][3][lane] = acc3;
}

__device__ __forceinline__ void unpair(int p, int& pa, int& pb) {
    int a = 0, rem = p;
    while (rem >= 16 - a) { rem -= 16 - a; ++a; }
    pa = a; pb = a + rem;
}

// ===== launch 1: combo table (level 12 memoized) + 3 parallel sorts + cnt zero =====
__global__ __launch_bounds__(256) void combo_sort_zero(const int* __restrict__ x_sym,
                                                       const float* __restrict__ W,
                                                       const float* __restrict__ b,
                                                       float* __restrict__ T,
                                                       int* __restrict__ order,
                                                       int* __restrict__ cnt) {
    __shared__ float  mean_s[GRP][MPAD];
    __shared__ float4 part_s[4][4][64];
    __shared__ int cnt_s[16], cur_s[16];
    const int t = threadIdx.x;
    const int w = t >> 6;
    const int lane = t & 63;
    const int bid = blockIdx.x;

    if (bid < 576) {  // ---- combo: T[s][pa][pb] for all pa<=pb, symmetric fill ----
        const int s = bid / 36;
        const int rem = bid % 36;
        const int chunk = rem >> 2;
        const int tile = rem & 3;
        {
            const int c = lane << 2;
            #pragma unroll
            for (int j = 0; j < 4; ++j) {
                const int p = chunk * 16 + w * 4 + j;
                float4 m = make_float4(0.f, 0.f, 0.f, 0.f);
                if (p < 136) {
                    int pa, pb; unpair(p, pa, pb);
                    const float4 ba = *(const float4*)(b + pa * DIM + c);
                    const float4 bb = *(const float4*)(b + pb * DIM + c);
                    m.x = 0.5f * (tanhf(ba.x) + tanhf(bb.x));
                    m.y = 0.5f * (tanhf(ba.y) + tanhf(bb.y));
                    m.z = 0.5f * (tanhf(ba.z) + tanhf(bb.z));
                    m.w = 0.5f * (tanhf(ba.w) + tanhf(bb.w));
                }
                *(float4*)(&mean_s[w * 4 + j][c]) = m;
            }
        }
        __syncthreads();
        const int ns4 = (lane >> 4) << 2;
        const int g4  = (lane & 15) << 2;
        gemm_core(W + ((size_t)s << 16) + (size_t)(w * 64) * DIM + tile * 64 + g4,
                  mean_s, part_s, w, lane);
        __syncthreads();
        const int p = chunk * 16 + ns4 + w;
        if (p < 136) {
            int pa, pb; unpair(p, pa, pb);
            float4 r        = part_s[0][w][lane];
            const float4 p1 = part_s[1][w][lane];
            const float4 p2 = part_s[2][w][lane];
            const float4 p3 = part_s[3][w][lane];
            const float4 bs = *(const float4*)(b + s * DIM + tile * 64 + g4);
            r.x = tanhf(r.x + p1.x + p2.x + p3.x + bs.x);
            r.y = tanhf(r.y + p1.y + p2.y + p3.y + bs.y);
            r.z = tanhf(r.z + p1.z + p2.z + p3.z + bs.z);
            r.w = tanhf(r.w + p1.w + p2.w + p3.w + bs.w);
            *(float4*)(T + (size_t)((s * 16 + pa) * 16 + pb) * DIM + tile * 64 + g4) = r;
            if (pa != pb)
                *(float4*)(T + (size_t)((s * 16 + pb) * 16 + pa) * DIM + tile * 64 + g4) = r;
        }
    } else if (bid <= 578) {  // ---- 3 parallel sorts: levels 11, 10, 9 ----
        const int li = bid - 576;
        const int d = 11 - li;
        const int off = (li == 0) ? O11 : (li == 1) ? O10 : O9;
        const int lo = (1 << d) - 1;
        const int n = 1 << d;
        for (int i = t; i < n + 240; i += 256) order[off + i] = -1;
        if (t < 16) cnt_s[t] = 0;
        __syncthreads();
        for (int i = t; i < n; i += 256) atomicAdd(&cnt_s[x_sym[lo + i]], 1);
        __syncthreads();
        if (t == 0) {
            int run = off;
            for (int s2 = 0; s2 < 16; ++s2) {
                cur_s[s2] = run;
                run += ((cnt_s[s2] + GRP - 1) / GRP) * GRP;
            }
        }
        __syncthreads();
        for (int i = t; i < n; i += 256) {
            const int pos = atomicAdd(&cur_s[x_sym[lo + i]], 1);
            order[pos] = lo + i;
        }
    } else {  // ---- bid 579: zero cnt (1024 lines); visible at LLC after launch ends ----
        for (int i = t; i < 1024 * CSTR; i += 256) cnt[i] = 0;
    }
}

// ===== launch 2: level 11, staging via combo table lookup =====
__global__ __launch_bounds__(256) void grouped_T(const int* __restrict__ x_sym,
                                                 const float* __restrict__ W,
                                                 const float* __restrict__ b,
                                                 float* __restrict__ enc,
                                                 const float* __restrict__ T,
                                                 const int* __restrict__ order) {
    const int base = (blockIdx.x >> 2) * GRP + O11;
    const int tile = blockIdx.x & 3;
    const int n0 = order[base];
    if (n0 < 0) return;
    const int s = x_sym[n0];
    const int t = threadIdx.x;
    const int w = t >> 6;
    const int lane = t & 63;
    __shared__ float  mean_s[GRP][MPAD];
    __shared__ float4 part_s[4][4][64];
    {
        const int c = lane << 2;
        #pragma unroll
        for (int j = 0; j < 4; ++j) {
            const int node = order[base + w * 4 + j];
            float4 m = make_float4(0.f, 0.f, 0.f, 0.f);
            if (node >= 0) {
                const int c0 = 2 * node + 1, c1 = c0 + 1;
                const float* r0 = T + (size_t)((x_sym[c0] * 16 + x_sym[2 * c0 + 1]) * 16
                                               + x_sym[2 * c0 + 2]) * DIM;
                const float* r1 = T + (size_t)((x_sym[c1] * 16 + x_sym[2 * c1 + 1]) * 16
                                               + x_sym[2 * c1 + 2]) * DIM;
                const float4 ea = *(const float4*)(r0 + c);
                const float4 eb = *(const float4*)(r1 + c);
                m.x = 0.5f * (ea.x + eb.x);
                m.y = 0.5f * (ea.y + eb.y);
                m.z = 0.5f * (ea.z + eb.z);
                m.w = 0.5f * (ea.w + eb.w);
            }
            *(float4*)(&mean_s[w * 4 + j][c]) = m;
        }
    }
    __syncthreads();
    const int ns4 = (lane >> 4) << 2;
    const int g4  = (lane & 15) << 2;
    gemm_core(W + ((size_t)s << 16) + (size_t)(w * 64) * DIM + tile * 64 + g4,
              mean_s, part_s, w, lane);
    __syncthreads();
    const int node_g = order[base + ns4 + w];
    if (node_g >= 0) {
        float4 r        = part_s[0][w][lane];
        const float4 p1 = part_s[1][w][lane];
        const float4 p2 = part_s[2][w][lane];
        const float4 p3 = part_s[3][w][lane];
        const float4 bs = *(const float4*)(b + s * DIM + tile * 64 + g4);
        r.x = tanhf(r.x + p1.x + p2.x + p3.x + bs.x);
        r.y = tanhf(r.y + p1.y + p2.y + p3.y + bs.y);
        r.z = tanhf(r.z + p1.z + p2.z + p3.z + bs.z);
        r.w = tanhf(r.w + p1.w + p2.w + p3.w + bs.w);
        *(float4*)(enc + (size_t)node_g * DIM + tile * 64 + g4) = r;
    }
}

// ===== launch 3 (and fallback): grouped level reading enc (cached) =====
__global__ __launch_bounds__(256) void grouped_enc(const int* __restrict__ x_sym,
                                                   const float* __restrict__ W,
                                                   const float* __restrict__ b,
                                                   float* __restrict__ enc,
                                                   const int* __restrict__ order,
                                                   int level_off) {
    const int base = (blockIdx.x >> 2) * GRP + level_off;
    const int tile = blockIdx.x & 3;
    const int n0 = order[base];
    if (n0 < 0) return;
    const int s = x_sym[n0];
    const int t = threadIdx.x;
    const int w = t >> 6;
    const int lane = t & 63;
    __shared__ float  mean_s[GRP][MPAD];
    __shared__ float4 part_s[4][4][64];
    {
        const int c = lane << 2;
        #pragma unroll
        for (int j = 0; j < 4; ++j) {
            const int node = order[base + w * 4 + j];
            float4 m = make_float4(0.f, 0.f, 0.f, 0.f);
            if (node >= 0) {
                const int c0 = 2 * node + 1;
                const float4 ea = *(const float4*)(enc + (size_t)c0 * DIM + c);
                const float4 eb = *(const float4*)(enc + (size_t)(c0 + 1) * DIM + c);
                m.x = 0.5f * (ea.x + eb.x);
                m.y = 0.5f * (ea.y + eb.y);
                m.z = 0.5f * (ea.z + eb.z);
                m.w = 0.5f * (ea.w + eb.w);
            }
            *(float4*)(&mean_s[w * 4 + j][c]) = m;
        }
    }
    __syncthreads();
    const int ns4 = (lane >> 4) << 2;
    const int g4  = (lane & 15) << 2;
    gemm_core(W + ((size_t)s << 16) + (size_t)(w * 64) * DIM + tile * 64 + g4,
              mean_s, part_s, w, lane);
    __syncthreads();
    const int node_g = order[base + ns4 + w];
    if (node_g >= 0) {
        float4 r        = part_s[0][w][lane];
        const float4 p1 = part_s[1][w][lane];
        const float4 p2 = part_s[2][w][lane];
        const float4 p3 = part_s[3][w][lane];
        const float4 bs = *(const float4*)(b + s * DIM + tile * 64 + g4);
        r.x = tanhf(r.x + p1.x + p2.x + p3.x + bs.x);
        r.y = tanhf(r.y + p1.y + p2.y + p3.y + bs.y);
        r.z = tanhf(r.z + p1.z + p2.z + p3.z + bs.z);
        r.w = tanhf(r.w + p1.w + p2.w + p3.w + bs.w);
        *(float4*)(enc + (size_t)node_g * DIM + tile * 64 + g4) = r;
    }
}

// ===== launch 4 (plain, exact-fit co-resident): level 9 + chained 8..0 + head =====
__global__ __launch_bounds__(256, 4) void tail_kernel(const int* __restrict__ x_sym,
                                                      const float* __restrict__ W,
                                                      const float* __restrict__ b,
                                                      float* __restrict__ enc,
                                                      const int* __restrict__ order,
                                                      int* __restrict__ cnt,
                                                      const float* __restrict__ W_out,
                                                      const float* __restrict__ b_out,
                                                      float* __restrict__ out) {
    __shared__ float  mean_s[GRP][MPAD];
    __shared__ float4 part_s[4][4][64];
    const int t = threadIdx.x;
    const int w = t >> 6;
    const int lane = t & 63;
    const int bid = blockIdx.x;

    // ---- phase 1: grouped level 9 (reads level-10 enc, cached; writes uncached) ----
    if (bid < G9_ITEMS) {
        const int base = (bid >> 2) * GRP + O9;
        const int tile = bid & 3;
        const int n0 = order[base];
        if (n0 >= 0) {
            const int s = x_sym[n0];
            const int c = lane << 2;
            #pragma unroll
            for (int j = 0; j < 4; ++j) {
                const int node = order[base + w * 4 + j];
                float4 m = make_float4(0.f, 0.f, 0.f, 0.f);
                if (node >= 0) {
                    const int c0 = 2 * node + 1;
                    const float4 ea = *(const float4*)(enc + (size_t)c0 * DIM + c);
                    const float4 eb = *(const float4*)(enc + (size_t)(c0 + 1) * DIM + c);
                    m.x = 0.5f * (ea.x + eb.x);
                    m.y = 0.5f * (ea.y + eb.y);
                    m.z = 0.5f * (ea.z + eb.z);
                    m.w = 0.5f * (ea.w + eb.w);
                }
                *(float4*)(&mean_s[w * 4 + j][c]) = m;
            }
            __syncthreads();
            const int ns4 = (lane >> 4) << 2;
            const int g4  = (lane & 15) << 2;
            gemm_core(W + ((size_t)s << 16) + (size_t)(w * 64) * DIM + tile * 64 + g4,
                      mean_s, part_s, w, lane);
            __syncthreads();
            const int node_g = order[base + ns4 + w];
            if (node_g >= 0) {
                float4 r        = part_s[0][w][lane];
                const float4 p1 = part_s[1][w][lane];
                const float4 p2 = part_s[2][w][lane];
                const float4 p3 = part_s[3][w][lane];
                const float4 bs = *(const float4*)(b + s * DIM + tile * 64 + g4);
                r.x = tanhf(r.x + p1.x + p2.x + p3.x + bs.x);
                r.y = tanhf(r.y + p1.y + p2.y + p3.y + bs.y);
                r.z = tanhf(r.z + p1.z + p2.z + p3.z + bs.z);
                r.w = tanhf(r.w + p1.w + p2.w + p3.w + bs.w);
                float* ep = enc + (size_t)node_g * DIM + tile * 64 + g4;
                st2(ep, r.x, r.y);
                st2(ep + 2, r.z, r.w);
            }
            __syncthreads();   // drain enc stores (vmcnt 0) before counting
            if (t < 16) {
                const int ng = order[base + t];
                if (ng >= 0) addi(&cnt[ng * CSTR]);
            }
        }
        __syncthreads();
    }

    // ---- phase 2: levels 8..0, cnt-chained (line-padded); W pinned-prefetched ----
    float* smean = (float*)&mean_s[0][0];
    float* spart = (float*)&part_s[0][0][0];
    for (int d = 8; d >= 0; --d) {
        const int items = 4 << d;
        if (bid >= items) return;   // retire forever
        const int node = (1 << d) - 1 + (bid >> 2);
        const int tile = bid & 3;
        const int c0 = 2 * node + 1;
        const int cc = tile * 64 + lane;
        const int s = x_sym[node];

        // prefetch this block's W tile into registers BEFORE the spin; "+v"
        // pins with memory clobber cannot cross the atomic spin and defeat
        // rematerialization (round 8/9: plain loads were sunk, VGPR stayed 52).
        const float* Wp = W + ((size_t)s << 16) + (size_t)(w * 64) * DIM + cc;
        float wreg[64];
        #pragma unroll
        for (int i = 0; i < 64; ++i) wreg[i] = Wp[(size_t)i * DIM];
        #pragma unroll
        for (int i = 0; i < 64; ++i) asm volatile("" : "+v"(wreg[i]) :: "memory");

        if (t < 2) spin4(&cnt[(c0 + t) * CSTR]);
        __syncthreads();

        if (t < 128) {   // stage mean: 8B uncached loads, 2 per thread
            const int o = t << 1;
            const float2 a = ld2(enc + (size_t)c0 * DIM + o);
            const float2 bb = ld2(enc + (size_t)(c0 + 1) * DIM + o);
            *(float2*)&smean[o] = make_float2(0.5f * (a.x + bb.x), 0.5f * (a.y + bb.y));
        }
        __syncthreads();

        float acc0 = 0.0f, acc1 = 0.0f;
        const float* sm = smean + w * 64;
        #pragma unroll
        for (int i = 0; i < 64; i += 2) {
            acc0 = fmaf(sm[i], wreg[i], acc0);
            acc1 = fmaf(sm[i + 1], wreg[i + 1], acc1);
        }
        spart[t] = acc0 + acc1;
        __syncthreads();
        if (t < 64) {
            float r = spart[t] + spart[t + 64] + spart[t + 128] + spart[t + 192];
            r += b[s * DIM + tile * 64 + t];
            st1f(enc + (size_t)node * DIM + tile * 64 + t, tanhf(r));
        }
        __syncthreads();   // drain stores before counting
        if (t == 0) addi(&cnt[node * CSTR]);
        __syncthreads();   // LDS reuse guard
    }

    // ---- head: block 0 ----
    if (bid == 0) {
        if (t == 0) spin4(&cnt[0]);
        __syncthreads();
        const float e = ld1(enc + t);
        float p[10];
        #pragma unroll
        for (int o = 0; o < 10; ++o) p[o] = e * W_out[t * 10 + o];
        #pragma unroll
        for (int o = 0; o < 10; ++o)
            #pragma unroll
            for (int k = 32; k >= 1; k >>= 1) p[o] += __shfl_xor(p[o], k, 64);
        float* hp = (float*)&part_s[0][0][0];
        if (lane == 0) {
            #pragma unroll
            for (int o = 0; o < 10; ++o) hp[w * 10 + o] = p[o];
        }
        __syncthreads();
        if (t < 10) out[t] = b_out[t] + hp[t] + hp[10 + t] + hp[20 + t] + hp[30 + t];
    }
}

// ======================= generic-shape fallbacks =======================
__global__ __launch_bounds__(256) void level_small(const int* __restrict__ x_sym,
                                                   const float* __restrict__ W,
                                                   const float* __restrict__ b,
                                                   float* __restrict__ enc,
                                                   int lo, int N) {
    const int node = lo + (blockIdx.x >> 2);
    const int tile = blockIdx.x & 3;
    const int t = threadIdx.x;
    const int lane = t & 63;
    const int c = tile * 64 + lane;
    __shared__ float mean_s[DIM];
    __shared__ float part[256];
    const int s = x_sym[node];
    const int c0 = 2 * node + 1;
    float m = 0.0f;
    if (c0 < N)
        m = 0.5f * (enc[(size_t)c0 * DIM + t] + enc[(size_t)(c0 + 1) * DIM + t]);
    mean_s[t] = m;
    __syncthreads();
    float acc = 0.0f;
    if (c0 < N) {
        const float* __restrict__ Ws = W + ((size_t)s << 16);
        const int d0 = (t >> 6) * 64;
        #pragma unroll 8
        for (int d = d0; d < d0 + 64; ++d)
            acc = fmaf(mean_s[d], Ws[d * DIM + c], acc);
    }
    part[t] = acc;
    __syncthreads();
    if (t < 64) {
        float r = part[t] + part[t + 64] + part[t + 128] + part[t + 192];
        r += b[s * DIM + c];
        enc[(size_t)node * DIM + c] = tanhf(r);
    }
}

__global__ __launch_bounds__(256) void level_big(const int* __restrict__ x_sym,
                                                 const float* __restrict__ W,
                                                 const float* __restrict__ b,
                                                 float* __restrict__ enc,
                                                 int lo, int N) {
    const int node = lo + blockIdx.x;
    const int e = threadIdx.x;
    __shared__ float mean_s[DIM];
    const int s = x_sym[node];
    const int c0 = 2 * node + 1;
    float acc = b[s * DIM + e];
    if (c0 < N) {
        mean_s[e] = 0.5f * (enc[(size_t)c0 * DIM + e] + enc[(size_t)(c0 + 1) * DIM + e]);
        __syncthreads();
        const float* __restrict__ Ws = W + ((size_t)s << 16);
        #pragma unroll 8
        for (int d = 0; d < DIM; ++d)
            acc = fmaf(mean_s[d], Ws[d * DIM + e], acc);
    }
    enc[(size_t)node * DIM + e] = tanhf(acc);
}

__global__ void out_kernel(const float* __restrict__ enc,
                           const float* __restrict__ W_out,
                           const float* __restrict__ b_out,
                           float* __restrict__ out, int outn) {
    const int o = threadIdx.x;
    if (o < outn) {
        float acc = b_out[o];
        for (int d = 0; d < DIM; ++d)
            acc = fmaf(enc[d], W_out[d * outn + o], acc);
        out[o] = acc;
    }
}

extern "C" void kernel_launch(void* const* d_in, const int* in_sizes, int n_in,
                              void* d_out, int out_size, void* d_ws, size_t ws_size,
                              hipStream_t stream) {
    const int*   x_sym = (const int*)d_in[0];
    const float* W     = (const float*)d_in[2];
    const float* b     = (const float*)d_in[3];
    const float* W_out = (const float*)d_in[4];
    const float* b_out = (const float*)d_in[5];
    float* out = (float*)d_out;
    float* enc = (float*)d_ws;                      // N x 256 fp32
    const int N = in_sizes[0];

    int depth = 0;
    while (((1 << depth) - 1) < N) ++depth;

    const size_t need = (size_t)16383 * DIM * 4 + (OTOT + 1024 * CSTR) * 4;
    if (N == (1 << 14) - 1 && out_size == 10 && ws_size >= need) {
        float* T   = enc + (size_t)8191 * DIM;       // combo table in unused leaf rows
        int* order = (int*)(enc + (size_t)N * DIM);  // OTOT ints
        int* cnt   = order + OTOT;                   // 1024 * CSTR ints (line-padded)

        combo_sort_zero<<<580, 256, 0, stream>>>(x_sym, W, b, T, order, cnt);
        grouped_T<<<G11_BLOCKS, 256, 0, stream>>>(x_sym, W, b, enc, T, order);
        grouped_enc<<<G10_BLOCKS, 256, 0, stream>>>(x_sym, W, b, enc, order, O10);
        // plain launch: 1024 blocks x 33KB LDS = exact-fit co-residency (4/CU x 256 CU)
        tail_kernel<<<NBLK, 256, 0, stream>>>(x_sym, W, b, enc, order, cnt,
                                              W_out, b_out, out);
    } else {
        for (int d = depth - 1; d >= 0; --d) {
            int lo = (1 << d) - 1;
            int n = (1 << d);
            if (lo + n > N) n = N - lo;
            if (n >= 256)
                level_big<<<n, 256, 0, stream>>>(x_sym, W, b, enc, lo, N);
            else
                level_small<<<n * 4, 256, 0, stream>>>(x_sym, W, b, enc, lo, N);
        }
        out_kernel<<<1, 64, 0, stream>>>(enc, W_out, b_out, out, out_size);
    }
}